// Round 1
// baseline (1196.903 us; speedup 1.0000x reference)
//
#include <hip/hip_runtime.h>
#include <hip/hip_bf16.h>
#include <math.h>

#define N_NODES 20000
#define N_EDGES 320000

// ---------------------------------------------------------------------------
// CSR build
// ---------------------------------------------------------------------------
__global__ void zero_int_kernel(int* __restrict__ p, int n) {
    int i = blockIdx.x * blockDim.x + threadIdx.x;
    if (i < n) p[i] = 0;
}

__global__ void count_deg_kernel(const int* __restrict__ dst, int* __restrict__ deg, int E) {
    int i = blockIdx.x * blockDim.x + threadIdx.x;
    if (i < E) atomicAdd(&deg[dst[i]], 1);
}

// single-block exclusive scan over n (n up to ~32K), writes offs[0..n] and cursor copy
__global__ __launch_bounds__(1024) void scan_kernel(const int* __restrict__ deg,
                                                    int* __restrict__ offs,
                                                    int* __restrict__ cursor, int n) {
    __shared__ int sd[1024];
    int tid = threadIdx.x;
    int carry = 0;
    for (int base = 0; base < n; base += 1024) {
        int i = base + tid;
        int v = (i < n) ? deg[i] : 0;
        sd[tid] = v;
        __syncthreads();
        for (int off = 1; off < 1024; off <<= 1) {
            int t = (tid >= off) ? sd[tid - off] : 0;
            __syncthreads();
            sd[tid] += t;
            __syncthreads();
        }
        int incl = sd[tid];
        int total = sd[1023];
        if (i < n) { int ex = carry + incl - v; offs[i] = ex; cursor[i] = ex; }
        carry += total;
        __syncthreads();
    }
    if (tid == 0) offs[n] = carry;
}

__global__ void scatter_kernel(const int* __restrict__ src, const int* __restrict__ dst,
                               int* __restrict__ cursor, int* __restrict__ csr_src,
                               int* __restrict__ csr_eid, int E) {
    int i = blockIdx.x * blockDim.x + threadIdx.x;
    if (i < E) {
        int pos = atomicAdd(&cursor[dst[i]], 1);
        csr_src[pos] = src[i];
        csr_eid[pos] = i;
    }
}

// ---------------------------------------------------------------------------
// fp32 tiled GEMM: C[M,Dn] = A[M,K] @ B[K,Dn] (+ b1 + b2)
// 64x64 tile, BK=16, 256 threads, 4x4 per thread
// ---------------------------------------------------------------------------
__global__ __launch_bounds__(256) void gemm_kernel(const float* __restrict__ A,
                                                   const float* __restrict__ B,
                                                   float* __restrict__ C,
                                                   const float* __restrict__ b1,
                                                   const float* __restrict__ b2,
                                                   int M, int K, int Dn) {
    __shared__ __align__(16) float As[16][64];   // [k][m]
    __shared__ __align__(16) float Bs[16][64];   // [k][n]
    int tid = threadIdx.x;
    int tx = tid & 15, ty = tid >> 4;
    int block_m = blockIdx.y * 64;
    int block_n = blockIdx.x * 64;

    float acc[4][4];
#pragma unroll
    for (int i = 0; i < 4; ++i)
#pragma unroll
        for (int j = 0; j < 4; ++j) acc[i][j] = 0.f;

    int a_row = tid >> 2;            // 0..63
    int a_kc  = (tid & 3) << 2;      // 0,4,8,12
    int b_krow = tid >> 4;           // 0..15
    int b_col  = (tid & 15) << 2;    // 0..60

    for (int k0 = 0; k0 < K; k0 += 16) {
        int gr = block_m + a_row;
        float4 av;
        if (gr < M) av = *(const float4*)(A + (size_t)gr * K + k0 + a_kc);
        else av = make_float4(0.f, 0.f, 0.f, 0.f);
        As[a_kc + 0][a_row] = av.x;
        As[a_kc + 1][a_row] = av.y;
        As[a_kc + 2][a_row] = av.z;
        As[a_kc + 3][a_row] = av.w;
        float4 bv = *(const float4*)(B + (size_t)(k0 + b_krow) * Dn + block_n + b_col);
        *(float4*)&Bs[b_krow][b_col] = bv;
        __syncthreads();
#pragma unroll
        for (int k = 0; k < 16; ++k) {
            float4 a4 = *(const float4*)&As[k][ty << 2];
            float4 b4 = *(const float4*)&Bs[k][tx << 2];
            float a[4] = {a4.x, a4.y, a4.z, a4.w};
            float b[4] = {b4.x, b4.y, b4.z, b4.w};
#pragma unroll
            for (int i = 0; i < 4; ++i)
#pragma unroll
                for (int j = 0; j < 4; ++j) acc[i][j] += a[i] * b[j];
        }
        __syncthreads();
    }

    int gc = block_n + (tx << 2);
    float bias[4] = {0.f, 0.f, 0.f, 0.f};
    if (b1) {
#pragma unroll
        for (int j = 0; j < 4; ++j) bias[j] += b1[gc + j];
    }
    if (b2) {
#pragma unroll
        for (int j = 0; j < 4; ++j) bias[j] += b2[gc + j];
    }
#pragma unroll
    for (int i = 0; i < 4; ++i) {
        int gr = block_m + (ty << 2) + i;
        if (gr < M) {
            float4 v = make_float4(acc[i][0] + bias[0], acc[i][1] + bias[1],
                                   acc[i][2] + bias[2], acc[i][3] + bias[3]);
            *(float4*)(C + (size_t)gr * Dn + gc) = v;
        }
    }
}

// ---------------------------------------------------------------------------
// per-edge attention score: e = leaky_relu(xl[src]+xr[dst], 0.2) . att
// one 64-lane wave per edge
// ---------------------------------------------------------------------------
__global__ __launch_bounds__(256) void edge_score_kernel(const float* __restrict__ xl,
                                                         const float* __restrict__ xr,
                                                         const int* __restrict__ src,
                                                         const int* __restrict__ dst,
                                                         const float* __restrict__ att,
                                                         float* __restrict__ e,
                                                         int E, int D) {
    int gid = blockIdx.x * blockDim.x + threadIdx.x;
    int w = gid >> 6;
    int lane = gid & 63;
    if (w >= E) return;
    int s = src[w], d = dst[w];
    const float4* xls = (const float4*)(xl + (size_t)s * D);
    const float4* xrd = (const float4*)(xr + (size_t)d * D);
    const float4* a4 = (const float4*)att;
    float acc = 0.f;
    int nd4 = D >> 2;
    for (int f = lane; f < nd4; f += 64) {
        float4 a = xls[f], b = xrd[f], t = a4[f];
        float v;
        v = a.x + b.x; v = v > 0.f ? v : 0.2f * v; acc += v * t.x;
        v = a.y + b.y; v = v > 0.f ? v : 0.2f * v; acc += v * t.y;
        v = a.z + b.z; v = v > 0.f ? v : 0.2f * v; acc += v * t.z;
        v = a.w + b.w; v = v > 0.f ? v : 0.2f * v; acc += v * t.w;
    }
#pragma unroll
    for (int o = 32; o > 0; o >>= 1) acc += __shfl_down(acc, o, 64);
    if (lane == 0) e[w] = acc;
}

// ---------------------------------------------------------------------------
// per-node segment softmax + weighted aggregation.
// out is pre-seeded with (h@Ws + bs + bc); we add sum(alpha * xl[src]) and relu.
// one block of 128 threads per destination node.
// ---------------------------------------------------------------------------
template <int D, int RELU>
__global__ __launch_bounds__(128) void aggregate_kernel(const float* __restrict__ xl,
                                                        const float* __restrict__ e,
                                                        const int* __restrict__ offs,
                                                        const int* __restrict__ csr_src,
                                                        const int* __restrict__ csr_eid,
                                                        float* __restrict__ out) {
    constexpr int T = 128;
    constexpr int F = D / T;
    constexpr int CH = 256;
    __shared__ float red[T];
    __shared__ float alpha_s[CH];
    __shared__ int src_s[CH];

    int n = blockIdx.x;
    int tid = threadIdx.x;
    int beg = offs[n], end = offs[n + 1];

    // pass 1: max
    float m = -INFINITY;
    for (int j = beg + tid; j < end; j += T) m = fmaxf(m, e[csr_eid[j]]);
    red[tid] = m;
    __syncthreads();
    for (int s = T / 2; s > 0; s >>= 1) {
        if (tid < s) red[tid] = fmaxf(red[tid], red[tid + s]);
        __syncthreads();
    }
    m = red[0];
    __syncthreads();

    // pass 2: sum of exp
    float sum = 0.f;
    for (int j = beg + tid; j < end; j += T) sum += expf(e[csr_eid[j]] - m);
    red[tid] = sum;
    __syncthreads();
    for (int s = T / 2; s > 0; s >>= 1) {
        if (tid < s) red[tid] += red[tid + s];
        __syncthreads();
    }
    float sinv = 1.0f / (red[0] + 1e-16f);
    __syncthreads();

    float acc[F];
#pragma unroll
    for (int i = 0; i < F; ++i) acc[i] = 0.f;

    for (int c0 = beg; c0 < end; c0 += CH) {
        int cn = end - c0;
        if (cn > CH) cn = CH;
        for (int j = tid; j < cn; j += T) {
            alpha_s[j] = expf(e[csr_eid[c0 + j]] - m) * sinv;
            src_s[j] = csr_src[c0 + j];
        }
        __syncthreads();
        for (int j = 0; j < cn; ++j) {
            float a = alpha_s[j];
            const float* row = xl + (size_t)src_s[j] * D;
#pragma unroll
            for (int i = 0; i < F; ++i) acc[i] += a * row[tid + i * T];
        }
        __syncthreads();
    }

#pragma unroll
    for (int i = 0; i < F; ++i) {
        size_t idx = (size_t)n * D + tid + i * T;
        float v = out[idx] + acc[i];
        if (RELU) v = fmaxf(v, 0.f);
        out[idx] = v;
    }
}

// ---------------------------------------------------------------------------
// host-side layer driver
// ---------------------------------------------------------------------------
static void run_layer(const float* hin, int K, int D,
                      const float* Wl, const float* Wr, const float* att,
                      const float* bc, const float* Ws, const float* bs,
                      float* xl, float* xr, float* evals,
                      const int* src, const int* dst,
                      const int* offs, const int* csr_src, const int* csr_eid,
                      float* out, int relu, hipStream_t stream) {
    dim3 ggrid(D / 64, (N_NODES + 63) / 64);
    hipLaunchKernelGGL(gemm_kernel, ggrid, dim3(256), 0, stream, hin, Wl, xl,
                       (const float*)nullptr, (const float*)nullptr, N_NODES, K, D);
    hipLaunchKernelGGL(gemm_kernel, ggrid, dim3(256), 0, stream, hin, Wr, xr,
                       (const float*)nullptr, (const float*)nullptr, N_NODES, K, D);
    hipLaunchKernelGGL(gemm_kernel, ggrid, dim3(256), 0, stream, hin, Ws, out,
                       bs, bc, N_NODES, K, D);

    int ethreads = N_EDGES * 64;
    hipLaunchKernelGGL(edge_score_kernel, dim3((ethreads + 255) / 256), dim3(256), 0, stream,
                       xl, xr, src, dst, att, evals, N_EDGES, D);

    if (D == 512) {
        if (relu)
            hipLaunchKernelGGL((aggregate_kernel<512, 1>), dim3(N_NODES), dim3(128), 0, stream,
                               xl, evals, offs, csr_src, csr_eid, out);
        else
            hipLaunchKernelGGL((aggregate_kernel<512, 0>), dim3(N_NODES), dim3(128), 0, stream,
                               xl, evals, offs, csr_src, csr_eid, out);
    } else if (D == 256) {
        if (relu)
            hipLaunchKernelGGL((aggregate_kernel<256, 1>), dim3(N_NODES), dim3(128), 0, stream,
                               xl, evals, offs, csr_src, csr_eid, out);
        else
            hipLaunchKernelGGL((aggregate_kernel<256, 0>), dim3(N_NODES), dim3(128), 0, stream,
                               xl, evals, offs, csr_src, csr_eid, out);
    } else {
        if (relu)
            hipLaunchKernelGGL((aggregate_kernel<128, 1>), dim3(N_NODES), dim3(128), 0, stream,
                               xl, evals, offs, csr_src, csr_eid, out);
        else
            hipLaunchKernelGGL((aggregate_kernel<128, 0>), dim3(N_NODES), dim3(128), 0, stream,
                               xl, evals, offs, csr_src, csr_eid, out);
    }
}

extern "C" void kernel_launch(void* const* d_in, const int* in_sizes, int n_in,
                              void* d_out, int out_size, void* d_ws, size_t ws_size,
                              hipStream_t stream) {
    const float* x = (const float*)d_in[0];
    const int* ei = (const int*)d_in[1];
    const int* src = ei;
    const int* dst = ei + N_EDGES;

    const float* Wl1 = (const float*)d_in[2];
    const float* Wr1 = (const float*)d_in[3];
    const float* att1 = (const float*)d_in[4];
    const float* bc1 = (const float*)d_in[5];
    const float* Ws1 = (const float*)d_in[6];
    const float* bs1 = (const float*)d_in[7];
    const float* Wl2 = (const float*)d_in[8];
    const float* Wr2 = (const float*)d_in[9];
    const float* att2 = (const float*)d_in[10];
    const float* bc2 = (const float*)d_in[11];
    const float* Ws2 = (const float*)d_in[12];
    const float* bs2 = (const float*)d_in[13];
    const float* Wl3 = (const float*)d_in[14];
    const float* Wr3 = (const float*)d_in[15];
    const float* att3 = (const float*)d_in[16];
    const float* bc3 = (const float*)d_in[17];
    const float* Ws3 = (const float*)d_in[18];
    const float* bs3 = (const float*)d_in[19];

    // workspace carve
    const size_t NF = (size_t)N_NODES * 512;
    float* xl    = (float*)d_ws;
    float* xr    = xl + NF;
    float* buf0  = xr + NF;
    float* buf1  = buf0 + NF;
    float* evals = buf1 + NF;
    int* deg     = (int*)(evals + N_EDGES);
    int* offs    = deg + N_NODES;
    int* cursor  = offs + N_NODES + 1;
    int* csr_src = cursor + N_NODES;
    int* csr_eid = csr_src + N_EDGES;
    size_t needed = (size_t)((char*)(csr_eid + N_EDGES) - (char*)d_ws);
    if (ws_size < needed) return;  // fail visibly rather than corrupt memory

    // CSR build (per call — no persistent state allowed)
    hipLaunchKernelGGL(zero_int_kernel, dim3((N_NODES + 255) / 256), dim3(256), 0, stream,
                       deg, N_NODES);
    hipLaunchKernelGGL(count_deg_kernel, dim3((N_EDGES + 255) / 256), dim3(256), 0, stream,
                       dst, deg, N_EDGES);
    hipLaunchKernelGGL(scan_kernel, dim3(1), dim3(1024), 0, stream, deg, offs, cursor, N_NODES);
    hipLaunchKernelGGL(scatter_kernel, dim3((N_EDGES + 255) / 256), dim3(256), 0, stream,
                       src, dst, cursor, csr_src, csr_eid, N_EDGES);

    // layer 1: 256 -> 512, relu
    run_layer(x, 256, 512, Wl1, Wr1, att1, bc1, Ws1, bs1,
              xl, xr, evals, src, dst, offs, csr_src, csr_eid, buf0, 1, stream);
    // layer 2: 512 -> 256, relu
    run_layer(buf0, 512, 256, Wl2, Wr2, att2, bc2, Ws2, bs2,
              xl, xr, evals, src, dst, offs, csr_src, csr_eid, buf1, 1, stream);
    // layer 3: 256 -> 128, no relu
    run_layer(buf1, 256, 128, Wl3, Wr3, att3, bc3, Ws3, bs3,
              xl, xr, evals, src, dst, offs, csr_src, csr_eid, (float*)d_out, 0, stream);
}

// Round 2
// 913.718 us; speedup vs baseline: 1.3099x; 1.3099x over previous
//
#include <hip/hip_runtime.h>
#include <hip/hip_bf16.h>
#include <math.h>

#define N_NODES 20000
#define N_EDGES 320000

typedef __bf16 bf16x8 __attribute__((ext_vector_type(8)));
typedef float f32x4 __attribute__((ext_vector_type(4)));

__device__ __forceinline__ unsigned short f2bf(float f) {
    unsigned int u = __float_as_uint(f);
    unsigned int r = u + 0x7FFFu + ((u >> 16) & 1u);   // round-to-nearest-even
    return (unsigned short)(r >> 16);
}

// ---------------------------------------------------------------------------
// CSR build
// ---------------------------------------------------------------------------
__global__ void zero_int_kernel(int* __restrict__ p, int n) {
    int i = blockIdx.x * blockDim.x + threadIdx.x;
    if (i < n) p[i] = 0;
}

__global__ void count_deg_kernel(const int* __restrict__ dst, int* __restrict__ deg, int E) {
    int i = blockIdx.x * blockDim.x + threadIdx.x;
    if (i < E) atomicAdd(&deg[dst[i]], 1);
}

__global__ __launch_bounds__(1024) void scan_kernel(const int* __restrict__ deg,
                                                    int* __restrict__ offs,
                                                    int* __restrict__ cursor, int n) {
    __shared__ int sd[1024];
    int tid = threadIdx.x;
    int carry = 0;
    for (int base = 0; base < n; base += 1024) {
        int i = base + tid;
        int v = (i < n) ? deg[i] : 0;
        sd[tid] = v;
        __syncthreads();
        for (int off = 1; off < 1024; off <<= 1) {
            int t = (tid >= off) ? sd[tid - off] : 0;
            __syncthreads();
            sd[tid] += t;
            __syncthreads();
        }
        int incl = sd[tid];
        int total = sd[1023];
        if (i < n) { int ex = carry + incl - v; offs[i] = ex; cursor[i] = ex; }
        carry += total;
        __syncthreads();
    }
    if (tid == 0) offs[n] = carry;
}

__global__ void scatter_kernel(const int* __restrict__ src, const int* __restrict__ dst,
                               int* __restrict__ cursor, int* __restrict__ csr_src,
                               int* __restrict__ csr_eid, int E) {
    int i = blockIdx.x * blockDim.x + threadIdx.x;
    if (i < E) {
        int pos = atomicAdd(&cursor[dst[i]], 1);
        csr_src[pos] = src[i];
        csr_eid[pos] = i;
    }
}

// ---------------------------------------------------------------------------
// conversions for bf16 MFMA GEMM
// ---------------------------------------------------------------------------
__global__ void convert_bf16_kernel(const float* __restrict__ in,
                                    unsigned short* __restrict__ out, int n) {
    int i = blockIdx.x * blockDim.x + threadIdx.x;
    int base = i * 4;
    if (base + 3 < n) {
        float4 v = *(const float4*)(in + base);
        out[base + 0] = f2bf(v.x);
        out[base + 1] = f2bf(v.y);
        out[base + 2] = f2bf(v.z);
        out[base + 3] = f2bf(v.w);
    } else {
        for (int k = base; k < n; ++k) out[k] = f2bf(in[k]);
    }
}

// W[K][D] fp32 -> Wt[D][K] bf16
__global__ void transpose_bf16_kernel(const float* __restrict__ W,
                                      unsigned short* __restrict__ Wt, int K, int D) {
    int i = blockIdx.x * blockDim.x + threadIdx.x;
    if (i < K * D) {
        int k = i / D, d = i - k * D;
        Wt[(size_t)d * K + k] = f2bf(W[i]);
    }
}

// ---------------------------------------------------------------------------
// bf16 MFMA GEMM: C[M,N] = A[M,K] @ B[K,N] (+ b1 + b2), Bt is B transposed [N][K]
// 128x128 tile, BK=32, 256 threads = 4 waves of 64x64, 16x16x32 MFMA
// ---------------------------------------------------------------------------
#define LDK 40  // padded k-stride (bf16 elems); 80B rows -> 2-way bank alias only

__global__ __launch_bounds__(256) void gemm_bf16_kernel(
        const unsigned short* __restrict__ A,   // [M][K] bf16
        const unsigned short* __restrict__ Bt,  // [N][K] bf16
        float* __restrict__ C,                  // [M][N] fp32
        const float* __restrict__ b1,
        const float* __restrict__ b2,
        int M, int K, int N) {
    __shared__ __align__(16) unsigned short Asl[128 * LDK];
    __shared__ __align__(16) unsigned short Bsl[128 * LDK];

    int tid = threadIdx.x;
    int wave = tid >> 6, lane = tid & 63;
    int q = lane >> 4, t = lane & 15;
    int wm = (wave & 1) * 64, wn = (wave >> 1) * 64;
    int bm = blockIdx.y * 128, bn = blockIdx.x * 128;

    f32x4 acc[4][4];
#pragma unroll
    for (int i = 0; i < 4; ++i)
#pragma unroll
        for (int j = 0; j < 4; ++j) acc[i][j] = (f32x4){0.f, 0.f, 0.f, 0.f};

    for (int k0 = 0; k0 < K; k0 += 32) {
        // stage A tile: 128 rows x 32 k (16B chunks; 512 chunks, 2 per thread)
#pragma unroll
        for (int c = tid; c < 512; c += 256) {
            int row = c >> 2, part = c & 3;
            int gr = bm + row;
            uint4 val = make_uint4(0u, 0u, 0u, 0u);
            if (gr < M) val = *(const uint4*)(A + (size_t)gr * K + k0 + part * 8);
            *(uint4*)(Asl + row * LDK + part * 8) = val;
        }
        // stage Bt tile: 128 n-rows x 32 k (N is a multiple of 128 -> no guard)
#pragma unroll
        for (int c = tid; c < 512; c += 256) {
            int row = c >> 2, part = c & 3;
            int gn = bn + row;
            uint4 val = *(const uint4*)(Bt + (size_t)gn * K + k0 + part * 8);
            *(uint4*)(Bsl + row * LDK + part * 8) = val;
        }
        __syncthreads();

        bf16x8 af[4], bfr[4];
#pragma unroll
        for (int i = 0; i < 4; ++i)
            af[i] = *(const bf16x8*)(Asl + (wm + i * 16 + t) * LDK + q * 8);
#pragma unroll
        for (int j = 0; j < 4; ++j)
            bfr[j] = *(const bf16x8*)(Bsl + (wn + j * 16 + t) * LDK + q * 8);
#pragma unroll
        for (int i = 0; i < 4; ++i)
#pragma unroll
            for (int j = 0; j < 4; ++j)
                acc[i][j] = __builtin_amdgcn_mfma_f32_16x16x32_bf16(af[i], bfr[j], acc[i][j], 0, 0, 0);
        __syncthreads();
    }

    // epilogue: C/D layout col=lane&15, row=quad*4+reg  [m89-verified]
#pragma unroll
    for (int j = 0; j < 4; ++j) {
        int col = bn + wn + j * 16 + t;
        float bias = 0.f;
        if (b1) bias += b1[col];
        if (b2) bias += b2[col];
#pragma unroll
        for (int i = 0; i < 4; ++i) {
            int row0 = bm + wm + i * 16 + q * 4;
#pragma unroll
            for (int r = 0; r < 4; ++r) {
                int row = row0 + r;
                if (row < M) C[(size_t)row * N + col] = acc[i][j][r] + bias;
            }
        }
    }
}

// ---------------------------------------------------------------------------
// per-edge attention score: e = leaky_relu(xl[src]+xr[dst], 0.2) . att
// ---------------------------------------------------------------------------
__global__ __launch_bounds__(256) void edge_score_kernel(const float* __restrict__ xl,
                                                         const float* __restrict__ xr,
                                                         const int* __restrict__ src,
                                                         const int* __restrict__ dst,
                                                         const float* __restrict__ att,
                                                         float* __restrict__ e,
                                                         int E, int D) {
    int gid = blockIdx.x * blockDim.x + threadIdx.x;
    int w = gid >> 6;
    int lane = gid & 63;
    if (w >= E) return;
    int s = src[w], d = dst[w];
    const float4* xls = (const float4*)(xl + (size_t)s * D);
    const float4* xrd = (const float4*)(xr + (size_t)d * D);
    const float4* a4 = (const float4*)att;
    float acc = 0.f;
    int nd4 = D >> 2;
    for (int f = lane; f < nd4; f += 64) {
        float4 a = xls[f], b = xrd[f], t = a4[f];
        float v;
        v = a.x + b.x; v = v > 0.f ? v : 0.2f * v; acc += v * t.x;
        v = a.y + b.y; v = v > 0.f ? v : 0.2f * v; acc += v * t.y;
        v = a.z + b.z; v = v > 0.f ? v : 0.2f * v; acc += v * t.z;
        v = a.w + b.w; v = v > 0.f ? v : 0.2f * v; acc += v * t.w;
    }
#pragma unroll
    for (int o = 32; o > 0; o >>= 1) acc += __shfl_down(acc, o, 64);
    if (lane == 0) e[w] = acc;
}

// ---------------------------------------------------------------------------
// per-node segment softmax + weighted aggregation (out pre-seeded with skip)
// ---------------------------------------------------------------------------
template <int D, int RELU>
__global__ __launch_bounds__(128) void aggregate_kernel(const float* __restrict__ xl,
                                                        const float* __restrict__ e,
                                                        const int* __restrict__ offs,
                                                        const int* __restrict__ csr_src,
                                                        const int* __restrict__ csr_eid,
                                                        float* __restrict__ out) {
    constexpr int T = 128;
    constexpr int F = D / T;
    constexpr int CH = 256;
    __shared__ float red[T];
    __shared__ float alpha_s[CH];
    __shared__ int src_s[CH];

    int n = blockIdx.x;
    int tid = threadIdx.x;
    int beg = offs[n], end = offs[n + 1];

    float m = -INFINITY;
    for (int j = beg + tid; j < end; j += T) m = fmaxf(m, e[csr_eid[j]]);
    red[tid] = m;
    __syncthreads();
    for (int s = T / 2; s > 0; s >>= 1) {
        if (tid < s) red[tid] = fmaxf(red[tid], red[tid + s]);
        __syncthreads();
    }
    m = red[0];
    __syncthreads();

    float sum = 0.f;
    for (int j = beg + tid; j < end; j += T) sum += expf(e[csr_eid[j]] - m);
    red[tid] = sum;
    __syncthreads();
    for (int s = T / 2; s > 0; s >>= 1) {
        if (tid < s) red[tid] += red[tid + s];
        __syncthreads();
    }
    float sinv = 1.0f / (red[0] + 1e-16f);
    __syncthreads();

    float acc[F];
#pragma unroll
    for (int i = 0; i < F; ++i) acc[i] = 0.f;

    for (int c0 = beg; c0 < end; c0 += CH) {
        int cn = end - c0;
        if (cn > CH) cn = CH;
        for (int j = tid; j < cn; j += T) {
            alpha_s[j] = expf(e[csr_eid[c0 + j]] - m) * sinv;
            src_s[j] = csr_src[c0 + j];
        }
        __syncthreads();
        for (int j = 0; j < cn; ++j) {
            float a = alpha_s[j];
            const float* row = xl + (size_t)src_s[j] * D;
#pragma unroll
            for (int i = 0; i < F; ++i) acc[i] += a * row[tid + i * T];
        }
        __syncthreads();
    }

#pragma unroll
    for (int i = 0; i < F; ++i) {
        size_t idx = (size_t)n * D + tid + i * T;
        float v = out[idx] + acc[i];
        if (RELU) v = fmaxf(v, 0.f);
        out[idx] = v;
    }
}

// ---------------------------------------------------------------------------
// host-side layer driver
// ---------------------------------------------------------------------------
static void run_layer(const float* hin, const unsigned short* hbf, int K, int D,
                      const unsigned short* Wlt, const unsigned short* Wrt,
                      const unsigned short* Wst,
                      const float* att, const float* bc, const float* bs,
                      float* xl, float* xr, float* evals,
                      const int* src, const int* dst,
                      const int* offs, const int* csr_src, const int* csr_eid,
                      float* out, int relu, hipStream_t stream) {
    // convert activations fp32 -> bf16
    int nconv = N_NODES * K;
    hipLaunchKernelGGL(convert_bf16_kernel, dim3((nconv / 4 + 255) / 256), dim3(256), 0, stream,
                       hin, (unsigned short*)hbf, nconv);

    dim3 ggrid(D / 128, (N_NODES + 127) / 128);
    hipLaunchKernelGGL(gemm_bf16_kernel, ggrid, dim3(256), 0, stream, hbf, Wlt, xl,
                       (const float*)nullptr, (const float*)nullptr, N_NODES, K, D);
    hipLaunchKernelGGL(gemm_bf16_kernel, ggrid, dim3(256), 0, stream, hbf, Wrt, xr,
                       (const float*)nullptr, (const float*)nullptr, N_NODES, K, D);
    hipLaunchKernelGGL(gemm_bf16_kernel, ggrid, dim3(256), 0, stream, hbf, Wst, out,
                       bs, bc, N_NODES, K, D);

    int ethreads = N_EDGES * 64;
    hipLaunchKernelGGL(edge_score_kernel, dim3((ethreads + 255) / 256), dim3(256), 0, stream,
                       xl, xr, src, dst, att, evals, N_EDGES, D);

    if (D == 512) {
        if (relu)
            hipLaunchKernelGGL((aggregate_kernel<512, 1>), dim3(N_NODES), dim3(128), 0, stream,
                               xl, evals, offs, csr_src, csr_eid, out);
        else
            hipLaunchKernelGGL((aggregate_kernel<512, 0>), dim3(N_NODES), dim3(128), 0, stream,
                               xl, evals, offs, csr_src, csr_eid, out);
    } else if (D == 256) {
        if (relu)
            hipLaunchKernelGGL((aggregate_kernel<256, 1>), dim3(N_NODES), dim3(128), 0, stream,
                               xl, evals, offs, csr_src, csr_eid, out);
        else
            hipLaunchKernelGGL((aggregate_kernel<256, 0>), dim3(N_NODES), dim3(128), 0, stream,
                               xl, evals, offs, csr_src, csr_eid, out);
    } else {
        if (relu)
            hipLaunchKernelGGL((aggregate_kernel<128, 1>), dim3(N_NODES), dim3(128), 0, stream,
                               xl, evals, offs, csr_src, csr_eid, out);
        else
            hipLaunchKernelGGL((aggregate_kernel<128, 0>), dim3(N_NODES), dim3(128), 0, stream,
                               xl, evals, offs, csr_src, csr_eid, out);
    }
}

extern "C" void kernel_launch(void* const* d_in, const int* in_sizes, int n_in,
                              void* d_out, int out_size, void* d_ws, size_t ws_size,
                              hipStream_t stream) {
    const float* x = (const float*)d_in[0];
    const int* ei = (const int*)d_in[1];
    const int* src = ei;
    const int* dst = ei + N_EDGES;

    const float* Wl1 = (const float*)d_in[2];
    const float* Wr1 = (const float*)d_in[3];
    const float* att1 = (const float*)d_in[4];
    const float* bc1 = (const float*)d_in[5];
    const float* Ws1 = (const float*)d_in[6];
    const float* bs1 = (const float*)d_in[7];
    const float* Wl2 = (const float*)d_in[8];
    const float* Wr2 = (const float*)d_in[9];
    const float* att2 = (const float*)d_in[10];
    const float* bc2 = (const float*)d_in[11];
    const float* Ws2 = (const float*)d_in[12];
    const float* bs2 = (const float*)d_in[13];
    const float* Wl3 = (const float*)d_in[14];
    const float* Wr3 = (const float*)d_in[15];
    const float* att3 = (const float*)d_in[16];
    const float* bc3 = (const float*)d_in[17];
    const float* Ws3 = (const float*)d_in[18];
    const float* bs3 = (const float*)d_in[19];

    // workspace carve
    const size_t NF = (size_t)N_NODES * 512;
    float* xl    = (float*)d_ws;
    float* xr    = xl + NF;
    float* buf0  = xr + NF;
    float* buf1  = buf0 + NF;
    float* evals = buf1 + NF;
    int* deg     = (int*)(evals + N_EDGES);
    int* offs    = deg + N_NODES;
    int* cursor  = offs + N_NODES + 1;
    int* csr_src = cursor + N_NODES;
    int* csr_eid = csr_src + N_EDGES;
    unsigned short* hbf = (unsigned short*)(csr_eid + N_EDGES);      // 20000*512 bf16
    unsigned short* wt  = hbf + NF;                                   // transposed bf16 weights
    unsigned short* Wl1t = wt;                  // 512*256
    unsigned short* Wr1t = Wl1t + 512 * 256;
    unsigned short* Ws1t = Wr1t + 512 * 256;
    unsigned short* Wl2t = Ws1t + 512 * 256;    // 256*512
    unsigned short* Wr2t = Wl2t + 256 * 512;
    unsigned short* Ws2t = Wr2t + 256 * 512;
    unsigned short* Wl3t = Ws2t + 256 * 512;    // 128*256
    unsigned short* Wr3t = Wl3t + 128 * 256;
    unsigned short* Ws3t = Wr3t + 128 * 256;
    size_t needed = (size_t)((char*)(Ws3t + 128 * 256) - (char*)d_ws);
    if (ws_size < needed) return;

    // CSR build
    hipLaunchKernelGGL(zero_int_kernel, dim3((N_NODES + 255) / 256), dim3(256), 0, stream,
                       deg, N_NODES);
    hipLaunchKernelGGL(count_deg_kernel, dim3((N_EDGES + 255) / 256), dim3(256), 0, stream,
                       dst, deg, N_EDGES);
    hipLaunchKernelGGL(scan_kernel, dim3(1), dim3(1024), 0, stream, deg, offs, cursor, N_NODES);
    hipLaunchKernelGGL(scatter_kernel, dim3((N_EDGES + 255) / 256), dim3(256), 0, stream,
                       src, dst, cursor, csr_src, csr_eid, N_EDGES);

    // weight transpose+convert (fp32 [K][D] -> bf16 [D][K])
    {
        int n1 = 256 * 512, n2 = 512 * 256, n3 = 256 * 128;
        dim3 b(256);
        hipLaunchKernelGGL(transpose_bf16_kernel, dim3((n1 + 255) / 256), b, 0, stream, Wl1, Wl1t, 256, 512);
        hipLaunchKernelGGL(transpose_bf16_kernel, dim3((n1 + 255) / 256), b, 0, stream, Wr1, Wr1t, 256, 512);
        hipLaunchKernelGGL(transpose_bf16_kernel, dim3((n1 + 255) / 256), b, 0, stream, Ws1, Ws1t, 256, 512);
        hipLaunchKernelGGL(transpose_bf16_kernel, dim3((n2 + 255) / 256), b, 0, stream, Wl2, Wl2t, 512, 256);
        hipLaunchKernelGGL(transpose_bf16_kernel, dim3((n2 + 255) / 256), b, 0, stream, Wr2, Wr2t, 512, 256);
        hipLaunchKernelGGL(transpose_bf16_kernel, dim3((n2 + 255) / 256), b, 0, stream, Ws2, Ws2t, 512, 256);
        hipLaunchKernelGGL(transpose_bf16_kernel, dim3((n3 + 255) / 256), b, 0, stream, Wl3, Wl3t, 256, 128);
        hipLaunchKernelGGL(transpose_bf16_kernel, dim3((n3 + 255) / 256), b, 0, stream, Wr3, Wr3t, 256, 128);
        hipLaunchKernelGGL(transpose_bf16_kernel, dim3((n3 + 255) / 256), b, 0, stream, Ws3, Ws3t, 256, 128);
    }

    // layer 1: 256 -> 512, relu
    run_layer(x, hbf, 256, 512, Wl1t, Wr1t, Ws1t, att1, bc1, bs1,
              xl, xr, evals, src, dst, offs, csr_src, csr_eid, buf0, 1, stream);
    // layer 2: 512 -> 256, relu
    run_layer(buf0, hbf, 512, 256, Wl2t, Wr2t, Ws2t, att2, bc2, bs2,
              xl, xr, evals, src, dst, offs, csr_src, csr_eid, buf1, 1, stream);
    // layer 3: 256 -> 128, no relu
    run_layer(buf1, hbf, 256, 128, Wl3t, Wr3t, Ws3t, att3, bc3, bs3,
              xl, xr, evals, src, dst, offs, csr_src, csr_eid, (float*)d_out, 0, stream);
}

// Round 3
// 542.336 us; speedup vs baseline: 2.2069x; 1.6848x over previous
//
#include <hip/hip_runtime.h>
#include <hip/hip_bf16.h>
#include <math.h>

#define N_NODES 20000
#define N_EDGES 320000

typedef __bf16 bf16x8 __attribute__((ext_vector_type(8)));
typedef float f32x4 __attribute__((ext_vector_type(4)));

__device__ __forceinline__ unsigned short f2bf(float f) {
    unsigned int u = __float_as_uint(f);
    unsigned int r = u + 0x7FFFu + ((u >> 16) & 1u);   // round-to-nearest-even
    return (unsigned short)(r >> 16);
}

// ---------------------------------------------------------------------------
// CSR build
// ---------------------------------------------------------------------------
__global__ void zero_int_kernel(int* __restrict__ p, int n) {
    int i = blockIdx.x * blockDim.x + threadIdx.x;
    if (i < n) p[i] = 0;
}

__global__ void count_deg_kernel(const int* __restrict__ dst, int* __restrict__ deg, int E) {
    int i = blockIdx.x * blockDim.x + threadIdx.x;
    if (i < E) atomicAdd(&deg[dst[i]], 1);
}

__global__ __launch_bounds__(1024) void scan_kernel(const int* __restrict__ deg,
                                                    int* __restrict__ offs,
                                                    int* __restrict__ cursor, int n) {
    __shared__ int sd[1024];
    int tid = threadIdx.x;
    int carry = 0;
    for (int base = 0; base < n; base += 1024) {
        int i = base + tid;
        int v = (i < n) ? deg[i] : 0;
        sd[tid] = v;
        __syncthreads();
        for (int off = 1; off < 1024; off <<= 1) {
            int t = (tid >= off) ? sd[tid - off] : 0;
            __syncthreads();
            sd[tid] += t;
            __syncthreads();
        }
        int incl = sd[tid];
        int total = sd[1023];
        if (i < n) { int ex = carry + incl - v; offs[i] = ex; cursor[i] = ex; }
        carry += total;
        __syncthreads();
    }
    if (tid == 0) offs[n] = carry;
}

__global__ void scatter_kernel(const int* __restrict__ src, const int* __restrict__ dst,
                               int* __restrict__ cursor, int* __restrict__ csr_src, int E) {
    int i = blockIdx.x * blockDim.x + threadIdx.x;
    if (i < E) {
        int pos = atomicAdd(&cursor[dst[i]], 1);
        csr_src[pos] = src[i];
    }
}

// ---------------------------------------------------------------------------
// conversions
// ---------------------------------------------------------------------------
__global__ void convert_bf16_kernel(const float* __restrict__ in,
                                    unsigned short* __restrict__ out, int n) {
    int i = blockIdx.x * blockDim.x + threadIdx.x;
    int base = i * 4;
    if (base + 3 < n) {
        float4 v = *(const float4*)(in + base);
        out[base + 0] = f2bf(v.x);
        out[base + 1] = f2bf(v.y);
        out[base + 2] = f2bf(v.z);
        out[base + 3] = f2bf(v.w);
    } else {
        for (int k = base; k < n; ++k) out[k] = f2bf(in[k]);
    }
}

// W[K][D] fp32 -> Wt[D][K] bf16
__global__ void transpose_bf16_kernel(const float* __restrict__ W,
                                      unsigned short* __restrict__ Wt, int K, int D) {
    int i = blockIdx.x * blockDim.x + threadIdx.x;
    if (i < K * D) {
        int k = i / D, d = i - k * D;
        Wt[(size_t)d * K + k] = f2bf(W[i]);
    }
}

// ---------------------------------------------------------------------------
// bf16 MFMA GEMM: C[M,N] = A[M,K] @ Bt[N][K]^T (+ b1 + b2)
// 128x128 tile, BK=32, 256 threads = 4 waves of 64x64, 16x16x32 MFMA
// OUTBF=1: write bf16 to Cb; OUTBF=0: write fp32 to Cf
// ---------------------------------------------------------------------------
#define LDK 40  // padded k-stride (bf16 elems); 2-way bank alias only (free, m136)

template <int OUTBF>
__global__ __launch_bounds__(256) void gemm_bf16_kernel(
        const unsigned short* __restrict__ A,   // [M][K] bf16
        const unsigned short* __restrict__ Bt,  // [N][K] bf16
        float* __restrict__ Cf,
        unsigned short* __restrict__ Cb,
        const float* __restrict__ b1,
        const float* __restrict__ b2,
        int M, int K, int N) {
    __shared__ __align__(16) unsigned short Asl[128 * LDK];
    __shared__ __align__(16) unsigned short Bsl[128 * LDK];

    int tid = threadIdx.x;
    int wave = tid >> 6, lane = tid & 63;
    int q = lane >> 4, t = lane & 15;
    int wm = (wave & 1) * 64, wn = (wave >> 1) * 64;
    int bm = blockIdx.y * 128, bn = blockIdx.x * 128;

    f32x4 acc[4][4];
#pragma unroll
    for (int i = 0; i < 4; ++i)
#pragma unroll
        for (int j = 0; j < 4; ++j) acc[i][j] = (f32x4){0.f, 0.f, 0.f, 0.f};

    for (int k0 = 0; k0 < K; k0 += 32) {
#pragma unroll
        for (int c = tid; c < 512; c += 256) {
            int row = c >> 2, part = c & 3;
            int gr = bm + row;
            uint4 val = make_uint4(0u, 0u, 0u, 0u);
            if (gr < M) val = *(const uint4*)(A + (size_t)gr * K + k0 + part * 8);
            *(uint4*)(Asl + row * LDK + part * 8) = val;
        }
#pragma unroll
        for (int c = tid; c < 512; c += 256) {
            int row = c >> 2, part = c & 3;
            int gn = bn + row;
            uint4 val = *(const uint4*)(Bt + (size_t)gn * K + k0 + part * 8);
            *(uint4*)(Bsl + row * LDK + part * 8) = val;
        }
        __syncthreads();

        bf16x8 af[4], bfr[4];
#pragma unroll
        for (int i = 0; i < 4; ++i)
            af[i] = *(const bf16x8*)(Asl + (wm + i * 16 + t) * LDK + q * 8);
#pragma unroll
        for (int j = 0; j < 4; ++j)
            bfr[j] = *(const bf16x8*)(Bsl + (wn + j * 16 + t) * LDK + q * 8);
#pragma unroll
        for (int i = 0; i < 4; ++i)
#pragma unroll
            for (int j = 0; j < 4; ++j)
                acc[i][j] = __builtin_amdgcn_mfma_f32_16x16x32_bf16(af[i], bfr[j], acc[i][j], 0, 0, 0);
        __syncthreads();
    }

    // epilogue: C/D layout col=lane&15, row=quad*4+reg  [m89-verified]
#pragma unroll
    for (int j = 0; j < 4; ++j) {
        int col = bn + wn + j * 16 + t;
        float bias = 0.f;
        if (b1) bias += b1[col];
        if (b2) bias += b2[col];
#pragma unroll
        for (int i = 0; i < 4; ++i) {
            int row0 = bm + wm + i * 16 + q * 4;
#pragma unroll
            for (int r = 0; r < 4; ++r) {
                int row = row0 + r;
                if (row < M) {
                    float v = acc[i][j][r] + bias;
                    if (OUTBF) Cb[(size_t)row * N + col] = f2bf(v);
                    else       Cf[(size_t)row * N + col] = v;
                }
            }
        }
    }
}

// ---------------------------------------------------------------------------
// fused per-node: edge scores + online softmax + weighted aggregation + skip.
// One 64-lane wave per destination node; 4 nodes per 256-thread block.
// xl/xr are bf16 [N][D]; seed is fp32 skip (h@Ws+bs+bc); output is bf16
// next-layer activation (WRITE_BF=1) or fp32 final (WRITE_BF=0).
// ---------------------------------------------------------------------------
template <int D, int WRITE_BF, int RELU>
__global__ __launch_bounds__(256) void fused_agg_kernel(
        const unsigned short* __restrict__ xl,
        const unsigned short* __restrict__ xr,
        const float* __restrict__ att,
        const int* __restrict__ offs,
        const int* __restrict__ csr_src,
        const float* __restrict__ seed,
        float* __restrict__ outf,
        unsigned short* __restrict__ outb) {
    constexpr int VPL = D / 64;
    typedef __bf16 bvec __attribute__((ext_vector_type(VPL)));

    int wave = threadIdx.x >> 6, lane = threadIdx.x & 63;
    int n = blockIdx.x * 4 + wave;
    if (n >= N_NODES) return;
    int beg = offs[n], end = offs[n + 1];

    float xr_f[VPL], att_f[VPL];
    bvec xrv = *(const bvec*)(xr + (size_t)n * D + lane * VPL);
#pragma unroll
    for (int v = 0; v < VPL; ++v) {
        xr_f[v] = (float)xrv[v];
        att_f[v] = att[lane * VPL + v];
    }

    float acc[VPL];
#pragma unroll
    for (int v = 0; v < VPL; ++v) acc[v] = 0.f;
    float m = -INFINITY, s = 0.f;

    for (int j = beg; j < end; ++j) {
        int srcn = csr_src[j];
        bvec xv = *(const bvec*)(xl + (size_t)srcn * D + lane * VPL);
        float xf[VPL];
        float part = 0.f;
#pragma unroll
        for (int v = 0; v < VPL; ++v) {
            xf[v] = (float)xv[v];
            float tv = xf[v] + xr_f[v];
            tv = tv > 0.f ? tv : 0.2f * tv;
            part += tv * att_f[v];
        }
#pragma unroll
        for (int o = 32; o > 0; o >>= 1) part += __shfl_xor(part, o, 64);

        if (part > m) {                    // wave-uniform branch
            float sc = __expf(m - part);   // first iter: exp(-inf)=0
            s *= sc;
#pragma unroll
            for (int v = 0; v < VPL; ++v) acc[v] *= sc;
            m = part;
        }
        float p = __expf(part - m);
        s += p;
#pragma unroll
        for (int v = 0; v < VPL; ++v) acc[v] += p * xf[v];
    }

    float sinv = 1.0f / (s + 1e-16f);
#pragma unroll
    for (int v = 0; v < VPL; ++v) {
        size_t idx = (size_t)n * D + lane * VPL + v;
        float val = seed[idx] + acc[v] * sinv;
        if (RELU) val = fmaxf(val, 0.f);
        if (WRITE_BF) outb[idx] = f2bf(val);
        else          outf[idx] = val;
    }
}

// ---------------------------------------------------------------------------
// host-side layer driver
// ---------------------------------------------------------------------------
static void run_layer(const unsigned short* hbf, int K, int D,
                      const unsigned short* Wlt, const unsigned short* Wrt,
                      const unsigned short* Wst,
                      const float* att, const float* bc, const float* bs,
                      unsigned short* xlb, unsigned short* xrb, float* seed,
                      const int* offs, const int* csr_src,
                      float* outf, unsigned short* outb, int relu,
                      hipStream_t stream) {
    dim3 ggrid(D / 128, (N_NODES + 127) / 128);
    hipLaunchKernelGGL((gemm_bf16_kernel<1>), ggrid, dim3(256), 0, stream, hbf, Wlt,
                       (float*)nullptr, xlb, (const float*)nullptr, (const float*)nullptr,
                       N_NODES, K, D);
    hipLaunchKernelGGL((gemm_bf16_kernel<1>), ggrid, dim3(256), 0, stream, hbf, Wrt,
                       (float*)nullptr, xrb, (const float*)nullptr, (const float*)nullptr,
                       N_NODES, K, D);
    hipLaunchKernelGGL((gemm_bf16_kernel<0>), ggrid, dim3(256), 0, stream, hbf, Wst,
                       seed, (unsigned short*)nullptr, bs, bc, N_NODES, K, D);

    dim3 agrid((N_NODES + 3) / 4);
    if (D == 512) {
        hipLaunchKernelGGL((fused_agg_kernel<512, 1, 1>), agrid, dim3(256), 0, stream,
                           xlb, xrb, att, offs, csr_src, seed, (float*)nullptr, outb);
    } else if (D == 256) {
        hipLaunchKernelGGL((fused_agg_kernel<256, 1, 1>), agrid, dim3(256), 0, stream,
                           xlb, xrb, att, offs, csr_src, seed, (float*)nullptr, outb);
    } else {
        hipLaunchKernelGGL((fused_agg_kernel<128, 0, 0>), agrid, dim3(256), 0, stream,
                           xlb, xrb, att, offs, csr_src, seed, outf, (unsigned short*)nullptr);
    }
}

extern "C" void kernel_launch(void* const* d_in, const int* in_sizes, int n_in,
                              void* d_out, int out_size, void* d_ws, size_t ws_size,
                              hipStream_t stream) {
    const float* x = (const float*)d_in[0];
    const int* ei = (const int*)d_in[1];
    const int* src = ei;
    const int* dst = ei + N_EDGES;

    const float* Wl1 = (const float*)d_in[2];
    const float* Wr1 = (const float*)d_in[3];
    const float* att1 = (const float*)d_in[4];
    const float* bc1 = (const float*)d_in[5];
    const float* Ws1 = (const float*)d_in[6];
    const float* bs1 = (const float*)d_in[7];
    const float* Wl2 = (const float*)d_in[8];
    const float* Wr2 = (const float*)d_in[9];
    const float* att2 = (const float*)d_in[10];
    const float* bc2 = (const float*)d_in[11];
    const float* Ws2 = (const float*)d_in[12];
    const float* bs2 = (const float*)d_in[13];
    const float* Wl3 = (const float*)d_in[14];
    const float* Wr3 = (const float*)d_in[15];
    const float* att3 = (const float*)d_in[16];
    const float* bc3 = (const float*)d_in[17];
    const float* Ws3 = (const float*)d_in[18];
    const float* bs3 = (const float*)d_in[19];

    // workspace carve (fp32 first, then bf16, then ints)
    const size_t NF = (size_t)N_NODES * 512;
    const size_t NH = (size_t)N_NODES * 256;
    float* seed = (float*)d_ws;                         // N x 512 fp32 (reused per layer)
    unsigned short* xlb = (unsigned short*)(seed + NF); // N x 512 bf16 (reused)
    unsigned short* xrb = xlb + NF;
    unsigned short* xbf = xrb + NF;                     // x as bf16: N x 256
    unsigned short* h1b = xbf + NH;                     // layer1 out: N x 512
    unsigned short* h2b = h1b + NF;                     // layer2 out: N x 256
    unsigned short* Wl1t = h2b + NH;                    // 512*256
    unsigned short* Wr1t = Wl1t + 512 * 256;
    unsigned short* Ws1t = Wr1t + 512 * 256;
    unsigned short* Wl2t = Ws1t + 512 * 256;            // 256*512
    unsigned short* Wr2t = Wl2t + 256 * 512;
    unsigned short* Ws2t = Wr2t + 256 * 512;
    unsigned short* Wl3t = Ws2t + 256 * 512;            // 128*256
    unsigned short* Wr3t = Wl3t + 128 * 256;
    unsigned short* Ws3t = Wr3t + 128 * 256;
    int* deg     = (int*)(Ws3t + 128 * 256);
    int* offs    = deg + N_NODES;
    int* cursor  = offs + N_NODES + 1;
    int* csr_src = cursor + N_NODES;
    size_t needed = (size_t)((char*)(csr_src + N_EDGES) - (char*)d_ws);
    if (ws_size < needed) return;

    // CSR build
    hipLaunchKernelGGL(zero_int_kernel, dim3((N_NODES + 255) / 256), dim3(256), 0, stream,
                       deg, N_NODES);
    hipLaunchKernelGGL(count_deg_kernel, dim3((N_EDGES + 255) / 256), dim3(256), 0, stream,
                       dst, deg, N_EDGES);
    hipLaunchKernelGGL(scan_kernel, dim3(1), dim3(1024), 0, stream, deg, offs, cursor, N_NODES);
    hipLaunchKernelGGL(scatter_kernel, dim3((N_EDGES + 255) / 256), dim3(256), 0, stream,
                       src, dst, cursor, csr_src, N_EDGES);

    // weight transpose+convert (fp32 [K][D] -> bf16 [D][K])
    {
        int n1 = 256 * 512, n2 = 512 * 256, n3 = 256 * 128;
        dim3 b(256);
        hipLaunchKernelGGL(transpose_bf16_kernel, dim3((n1 + 255) / 256), b, 0, stream, Wl1, Wl1t, 256, 512);
        hipLaunchKernelGGL(transpose_bf16_kernel, dim3((n1 + 255) / 256), b, 0, stream, Wr1, Wr1t, 256, 512);
        hipLaunchKernelGGL(transpose_bf16_kernel, dim3((n1 + 255) / 256), b, 0, stream, Ws1, Ws1t, 256, 512);
        hipLaunchKernelGGL(transpose_bf16_kernel, dim3((n2 + 255) / 256), b, 0, stream, Wl2, Wl2t, 512, 256);
        hipLaunchKernelGGL(transpose_bf16_kernel, dim3((n2 + 255) / 256), b, 0, stream, Wr2, Wr2t, 512, 256);
        hipLaunchKernelGGL(transpose_bf16_kernel, dim3((n2 + 255) / 256), b, 0, stream, Ws2, Ws2t, 512, 256);
        hipLaunchKernelGGL(transpose_bf16_kernel, dim3((n3 + 255) / 256), b, 0, stream, Wl3, Wl3t, 256, 128);
        hipLaunchKernelGGL(transpose_bf16_kernel, dim3((n3 + 255) / 256), b, 0, stream, Wr3, Wr3t, 256, 128);
        hipLaunchKernelGGL(transpose_bf16_kernel, dim3((n3 + 255) / 256), b, 0, stream, Ws3, Ws3t, 256, 128);
    }

    // x -> bf16
    {
        int nconv = N_NODES * 256;
        hipLaunchKernelGGL(convert_bf16_kernel, dim3((nconv / 4 + 255) / 256), dim3(256), 0, stream,
                           x, xbf, nconv);
    }

    // layer 1: 256 -> 512, relu, bf16 out
    run_layer(xbf, 256, 512, Wl1t, Wr1t, Ws1t, att1, bc1, bs1,
              xlb, xrb, seed, offs, csr_src, (float*)nullptr, h1b, 1, stream);
    // layer 2: 512 -> 256, relu, bf16 out
    run_layer(h1b, 512, 256, Wl2t, Wr2t, Ws2t, att2, bc2, bs2,
              xlb, xrb, seed, offs, csr_src, (float*)nullptr, h2b, 1, stream);
    // layer 3: 256 -> 128, no relu, fp32 out; seed directly in d_out
    run_layer(h2b, 256, 128, Wl3t, Wr3t, Ws3t, att3, bc3, bs3,
              xlb, xrb, (float*)d_out, offs, csr_src, (float*)d_out,
              (unsigned short*)nullptr, 0, stream);
}

// Round 4
// 439.856 us; speedup vs baseline: 2.7211x; 1.2330x over previous
//
#include <hip/hip_runtime.h>
#include <hip/hip_bf16.h>
#include <math.h>

#define N_NODES 20000
#define N_EDGES 320000

typedef __bf16 bf16x8 __attribute__((ext_vector_type(8)));
typedef float f32x4 __attribute__((ext_vector_type(4)));

__device__ __forceinline__ unsigned short f2bf(float f) {
    unsigned int u = __float_as_uint(f);
    unsigned int r = u + 0x7FFFu + ((u >> 16) & 1u);   // round-to-nearest-even
    return (unsigned short)(r >> 16);
}

// ---------------------------------------------------------------------------
// CSR build
// ---------------------------------------------------------------------------
__global__ void zero_int_kernel(int* __restrict__ p, int n) {
    int i = blockIdx.x * blockDim.x + threadIdx.x;
    if (i < n) p[i] = 0;
}

__global__ void count_deg_kernel(const int* __restrict__ dst, int* __restrict__ deg, int E) {
    int i = blockIdx.x * blockDim.x + threadIdx.x;
    if (i < E) atomicAdd(&deg[dst[i]], 1);
}

// single-pass scan: thread t serially scans its 20-elem chunk, one LDS scan of totals
#define SCAN_T 1024
#define SCAN_C 20   // ceil(20000/1024)
__global__ __launch_bounds__(1024) void scan_kernel(const int* __restrict__ deg,
                                                    int* __restrict__ offs,
                                                    int* __restrict__ cursor, int n) {
    __shared__ int sd[SCAN_T];
    int t = threadIdx.x;
    int base = t * SCAN_C;
    int vex[SCAN_C];
    int run = 0;
#pragma unroll
    for (int k = 0; k < SCAN_C; ++k) {
        int i = base + k;
        int d = (i < n) ? deg[i] : 0;
        vex[k] = run;          // local exclusive prefix
        run += d;
    }
    sd[t] = run;
    __syncthreads();
    for (int off = 1; off < SCAN_T; off <<= 1) {
        int x = (t >= off) ? sd[t - off] : 0;
        __syncthreads();
        sd[t] += x;
        __syncthreads();
    }
    int excl = sd[t] - run;
#pragma unroll
    for (int k = 0; k < SCAN_C; ++k) {
        int i = base + k;
        if (i < n) { int e = excl + vex[k]; offs[i] = e; cursor[i] = e; }
    }
    if (t == SCAN_T - 1) offs[n] = sd[t];
}

__global__ void scatter_kernel(const int* __restrict__ src, const int* __restrict__ dst,
                               int* __restrict__ cursor, int* __restrict__ csr_src, int E) {
    int i = blockIdx.x * blockDim.x + threadIdx.x;
    if (i < E) {
        int pos = atomicAdd(&cursor[dst[i]], 1);
        csr_src[pos] = src[i];
    }
}

// ---------------------------------------------------------------------------
// conversions
// ---------------------------------------------------------------------------
__global__ void convert_bf16_kernel(const float* __restrict__ in,
                                    unsigned short* __restrict__ out, int n) {
    int i = blockIdx.x * blockDim.x + threadIdx.x;
    int base = i * 4;
    if (base + 3 < n) {
        float4 v = *(const float4*)(in + base);
        out[base + 0] = f2bf(v.x);
        out[base + 1] = f2bf(v.y);
        out[base + 2] = f2bf(v.z);
        out[base + 3] = f2bf(v.w);
    } else {
        for (int k = base; k < n; ++k) out[k] = f2bf(in[k]);
    }
}

// all 9 weight transposes (fp32 [K][D] -> bf16 [D][K]) in one launch
struct TransJobs {
    const float* W[9];
    unsigned short* Wt[9];
    int K[9];
    int D[9];
    int beg[10];
};
__global__ void transpose_all_kernel(TransJobs jb) {
    int i = blockIdx.x * blockDim.x + threadIdx.x;
    if (i >= jb.beg[9]) return;
    int job = 0;
    while (i >= jb.beg[job + 1]) ++job;
    int local = i - jb.beg[job];
    int D = jb.D[job], K = jb.K[job];
    int k = local / D, d = local - k * D;
    jb.Wt[job][(size_t)d * K + k] = f2bf(jb.W[job][local]);
}

// ---------------------------------------------------------------------------
// fused 3-in-1 bf16 MFMA GEMM:
//   [xl | xr | seed] = A[M,K] @ Btcat[3D,K]^T  (bias bs+bc on seed segment)
// 128x128 tile, BK=64, 256 threads = 4 waves of 64x64, 16x16x32 MFMA
// seg = bn/D routes output: 0->xlb (bf16), 1->xrb (bf16), 2->seed (bf16 or fp32)
// ---------------------------------------------------------------------------
#define GBK 64
#define LDK 72  // padded k-stride (bf16 elems)

template <int SEED_F32>
__global__ __launch_bounds__(256) void gemm3_kernel(
        const unsigned short* __restrict__ A,    // [M][K] bf16
        const unsigned short* __restrict__ Bt,   // [3D][K] bf16 (Wl^T|Wr^T|Ws^T)
        unsigned short* __restrict__ xlb,        // [M][D] bf16
        unsigned short* __restrict__ xrb,        // [M][D] bf16
        unsigned short* __restrict__ seedb,      // [M][D] bf16 (SEED_F32==0)
        float* __restrict__ seedf,               // [M][D] fp32 (SEED_F32==1)
        const float* __restrict__ b1,
        const float* __restrict__ b2,
        int M, int K, int D) {
    __shared__ __align__(16) unsigned short Asl[128 * LDK];
    __shared__ __align__(16) unsigned short Bsl[128 * LDK];

    int tid = threadIdx.x;
    int wave = tid >> 6, lane = tid & 63;
    int q = lane >> 4, t = lane & 15;
    int wm = (wave & 1) * 64, wn = (wave >> 1) * 64;
    int bm = blockIdx.y * 128;
    int bn_all = blockIdx.x * 128;
    int seg = bn_all / D;            // D is a multiple of 128 -> block-uniform
    int bn = bn_all - seg * D;

    f32x4 acc[4][4];
#pragma unroll
    for (int i = 0; i < 4; ++i)
#pragma unroll
        for (int j = 0; j < 4; ++j) acc[i][j] = (f32x4){0.f, 0.f, 0.f, 0.f};

    for (int k0 = 0; k0 < K; k0 += GBK) {
        // stage A tile: 128 rows x 64 k = 1024 16B chunks, 4 per thread
#pragma unroll
        for (int c = tid; c < 1024; c += 256) {
            int row = c >> 3, part = c & 7;
            int gr = bm + row; if (gr >= M) gr = M - 1;   // clamp (rows >= M discarded)
            uint4 val = *(const uint4*)(A + (size_t)gr * K + k0 + part * 8);
            *(uint4*)(Asl + row * LDK + part * 8) = val;
        }
        // stage Bt tile (3D is a multiple of 128 -> no guard)
#pragma unroll
        for (int c = tid; c < 1024; c += 256) {
            int row = c >> 3, part = c & 7;
            uint4 val = *(const uint4*)(Bt + (size_t)(bn_all + row) * K + k0 + part * 8);
            *(uint4*)(Bsl + row * LDK + part * 8) = val;
        }
        __syncthreads();

#pragma unroll
        for (int h = 0; h < 2; ++h) {   // two K=32 halves of the BK=64 tile
            bf16x8 af[4], bfr[4];
#pragma unroll
            for (int i = 0; i < 4; ++i)
                af[i] = *(const bf16x8*)(Asl + (wm + i * 16 + t) * LDK + h * 32 + q * 8);
#pragma unroll
            for (int j = 0; j < 4; ++j)
                bfr[j] = *(const bf16x8*)(Bsl + (wn + j * 16 + t) * LDK + h * 32 + q * 8);
#pragma unroll
            for (int i = 0; i < 4; ++i)
#pragma unroll
                for (int j = 0; j < 4; ++j)
                    acc[i][j] = __builtin_amdgcn_mfma_f32_16x16x32_bf16(af[i], bfr[j], acc[i][j], 0, 0, 0);
        }
        __syncthreads();
    }

    // epilogue: C/D layout col=lane&15, row=quad*4+reg  [m89-verified]
#pragma unroll
    for (int j = 0; j < 4; ++j) {
        int col = bn + wn + j * 16 + t;
        float bias = 0.f;
        if (seg == 2) bias = b1[col] + b2[col];
#pragma unroll
        for (int i = 0; i < 4; ++i) {
            int row0 = bm + wm + i * 16 + q * 4;
#pragma unroll
            for (int r = 0; r < 4; ++r) {
                int row = row0 + r;
                if (row < M) {
                    float v = acc[i][j][r] + bias;
                    size_t idx = (size_t)row * D + col;
                    if (seg == 0)      xlb[idx] = f2bf(v);
                    else if (seg == 1) xrb[idx] = f2bf(v);
                    else if (SEED_F32) seedf[idx] = v;
                    else               seedb[idx] = f2bf(v);
                }
            }
        }
    }
}

// ---------------------------------------------------------------------------
// fused per-node: edge scores + online softmax + aggregation + skip.
// One 64-lane wave per destination node, 2 edges per iteration (ILP),
// always-rescale online softmax (exp(-inf)=0 handles init).
// ---------------------------------------------------------------------------
template <int D, int SEED_BF, int WRITE_BF, int RELU>
__global__ __launch_bounds__(256) void fused_agg_kernel(
        const unsigned short* __restrict__ xl,
        const unsigned short* __restrict__ xr,
        const float* __restrict__ att,
        const int* __restrict__ offs,
        const int* __restrict__ csr_src,
        const unsigned short* __restrict__ seedb,
        const float* __restrict__ seedf,
        float* __restrict__ outf,
        unsigned short* __restrict__ outb) {
    constexpr int VPL = D / 64;
    typedef __bf16 bvec __attribute__((ext_vector_type(VPL)));

    int wave = threadIdx.x >> 6, lane = threadIdx.x & 63;
    int n = blockIdx.x * 4 + wave;
    if (n >= N_NODES) return;
    int beg = offs[n], end = offs[n + 1];

    float xr_f[VPL], att_f[VPL];
    bvec xrv = *(const bvec*)(xr + (size_t)n * D + lane * VPL);
#pragma unroll
    for (int v = 0; v < VPL; ++v) {
        xr_f[v] = (float)xrv[v];
        att_f[v] = att[lane * VPL + v];
    }

    float acc[VPL];
#pragma unroll
    for (int v = 0; v < VPL; ++v) acc[v] = 0.f;
    float m = -INFINITY, s = 0.f;

    int j = beg;
    for (; j + 1 < end; j += 2) {
        int s0 = csr_src[j], s1 = csr_src[j + 1];
        bvec xv0 = *(const bvec*)(xl + (size_t)s0 * D + lane * VPL);
        bvec xv1 = *(const bvec*)(xl + (size_t)s1 * D + lane * VPL);
        float xf0[VPL], xf1[VPL];
        float p0 = 0.f, p1 = 0.f;
#pragma unroll
        for (int v = 0; v < VPL; ++v) {
            xf0[v] = (float)xv0[v];
            xf1[v] = (float)xv1[v];
            float t0 = xf0[v] + xr_f[v];
            float t1 = xf1[v] + xr_f[v];
            t0 = fmaxf(t0, 0.2f * t0);      // leaky_relu(t) == max(t, 0.2t)
            t1 = fmaxf(t1, 0.2f * t1);
            p0 += t0 * att_f[v];
            p1 += t1 * att_f[v];
        }
#pragma unroll
        for (int o = 32; o > 0; o >>= 1) {   // two interleaved allreduce chains
            p0 += __shfl_xor(p0, o, 64);
            p1 += __shfl_xor(p1, o, 64);
        }
        float mn = fmaxf(m, fmaxf(p0, p1));
        float sc = __expf(m - mn);           // first iter: exp(-inf)=0
        float e0 = __expf(p0 - mn);
        float e1 = __expf(p1 - mn);
        s = s * sc + e0 + e1;
#pragma unroll
        for (int v = 0; v < VPL; ++v)
            acc[v] = acc[v] * sc + e0 * xf0[v] + e1 * xf1[v];
        m = mn;
    }
    if (j < end) {   // odd tail
        int s0 = csr_src[j];
        bvec xv0 = *(const bvec*)(xl + (size_t)s0 * D + lane * VPL);
        float xf0[VPL];
        float p0 = 0.f;
#pragma unroll
        for (int v = 0; v < VPL; ++v) {
            xf0[v] = (float)xv0[v];
            float t0 = xf0[v] + xr_f[v];
            t0 = fmaxf(t0, 0.2f * t0);
            p0 += t0 * att_f[v];
        }
#pragma unroll
        for (int o = 32; o > 0; o >>= 1) p0 += __shfl_xor(p0, o, 64);
        float mn = fmaxf(m, p0);
        float sc = __expf(m - mn);
        float e0 = __expf(p0 - mn);
        s = s * sc + e0;
#pragma unroll
        for (int v = 0; v < VPL; ++v) acc[v] = acc[v] * sc + e0 * xf0[v];
        m = mn;
    }

    float sinv = 1.0f / (s + 1e-16f);
    size_t base = (size_t)n * D + lane * VPL;
    float sd[VPL];
    if (SEED_BF) {
        bvec sv = *(const bvec*)(seedb + base);
#pragma unroll
        for (int v = 0; v < VPL; ++v) sd[v] = (float)sv[v];
    } else {
#pragma unroll
        for (int v = 0; v < VPL; ++v) sd[v] = seedf[base + v];
    }
#pragma unroll
    for (int v = 0; v < VPL; ++v) {
        float val = sd[v] + acc[v] * sinv;
        if (RELU) val = fmaxf(val, 0.f);
        if (WRITE_BF) outb[base + v] = f2bf(val);
        else          outf[base + v] = val;
    }
}

// ---------------------------------------------------------------------------
// host-side layer driver
// ---------------------------------------------------------------------------
static void run_layer(const unsigned short* hbf, int K, int D,
                      const unsigned short* Wcat,
                      const float* att, const float* bc, const float* bs,
                      unsigned short* xlb, unsigned short* xrb,
                      unsigned short* seedb, float* seedf,
                      const int* offs, const int* csr_src,
                      float* outf, unsigned short* outb, int final_layer,
                      hipStream_t stream) {
    dim3 ggrid(3 * D / 128, (N_NODES + 127) / 128);
    if (final_layer)
        hipLaunchKernelGGL((gemm3_kernel<1>), ggrid, dim3(256), 0, stream, hbf, Wcat,
                           xlb, xrb, (unsigned short*)nullptr, seedf, bs, bc, N_NODES, K, D);
    else
        hipLaunchKernelGGL((gemm3_kernel<0>), ggrid, dim3(256), 0, stream, hbf, Wcat,
                           xlb, xrb, seedb, (float*)nullptr, bs, bc, N_NODES, K, D);

    dim3 agrid((N_NODES + 3) / 4);
    if (D == 512) {
        hipLaunchKernelGGL((fused_agg_kernel<512, 1, 1, 1>), agrid, dim3(256), 0, stream,
                           xlb, xrb, att, offs, csr_src, seedb, (const float*)nullptr,
                           (float*)nullptr, outb);
    } else if (D == 256) {
        hipLaunchKernelGGL((fused_agg_kernel<256, 1, 1, 1>), agrid, dim3(256), 0, stream,
                           xlb, xrb, att, offs, csr_src, seedb, (const float*)nullptr,
                           (float*)nullptr, outb);
    } else {
        hipLaunchKernelGGL((fused_agg_kernel<128, 0, 0, 0>), agrid, dim3(256), 0, stream,
                           xlb, xrb, att, offs, csr_src, (const unsigned short*)nullptr, seedf,
                           outf, (unsigned short*)nullptr);
    }
}

extern "C" void kernel_launch(void* const* d_in, const int* in_sizes, int n_in,
                              void* d_out, int out_size, void* d_ws, size_t ws_size,
                              hipStream_t stream) {
    const float* x = (const float*)d_in[0];
    const int* ei = (const int*)d_in[1];
    const int* src = ei;
    const int* dst = ei + N_EDGES;

    const float* Wl1 = (const float*)d_in[2];
    const float* Wr1 = (const float*)d_in[3];
    const float* att1 = (const float*)d_in[4];
    const float* bc1 = (const float*)d_in[5];
    const float* Ws1 = (const float*)d_in[6];
    const float* bs1 = (const float*)d_in[7];
    const float* Wl2 = (const float*)d_in[8];
    const float* Wr2 = (const float*)d_in[9];
    const float* att2 = (const float*)d_in[10];
    const float* bc2 = (const float*)d_in[11];
    const float* Ws2 = (const float*)d_in[12];
    const float* bs2 = (const float*)d_in[13];
    const float* Wl3 = (const float*)d_in[14];
    const float* Wr3 = (const float*)d_in[15];
    const float* att3 = (const float*)d_in[16];
    const float* bc3 = (const float*)d_in[17];
    const float* Ws3 = (const float*)d_in[18];
    const float* bs3 = (const float*)d_in[19];

    // workspace carve
    const size_t NF = (size_t)N_NODES * 512;
    const size_t NH = (size_t)N_NODES * 256;
    unsigned short* xlb   = (unsigned short*)d_ws;      // N x 512 bf16 (reused per layer)
    unsigned short* xrb   = xlb + NF;
    unsigned short* seedb = xrb + NF;                   // N x 512 bf16 (layers 1-2)
    unsigned short* xbf   = seedb + NF;                 // x as bf16: N x 256
    unsigned short* h1b   = xbf + NH;                   // layer1 out: N x 512
    unsigned short* h2b   = h1b + NF;                   // layer2 out: N x 256
    unsigned short* Wcat1 = h2b + NH;                   // 3 x 512 x 256
    unsigned short* Wcat2 = Wcat1 + 3 * 512 * 256;      // 3 x 256 x 512
    unsigned short* Wcat3 = Wcat2 + 3 * 256 * 512;      // 3 x 128 x 256
    int* deg     = (int*)(Wcat3 + 3 * 128 * 256);
    int* offs    = deg + N_NODES;
    int* cursor  = offs + N_NODES + 1;
    int* csr_src = cursor + N_NODES;
    size_t needed = (size_t)((char*)(csr_src + N_EDGES) - (char*)d_ws);
    if (ws_size < needed) return;

    // CSR build
    hipLaunchKernelGGL(zero_int_kernel, dim3((N_NODES + 255) / 256), dim3(256), 0, stream,
                       deg, N_NODES);
    hipLaunchKernelGGL(count_deg_kernel, dim3((N_EDGES + 255) / 256), dim3(256), 0, stream,
                       dst, deg, N_EDGES);
    hipLaunchKernelGGL(scan_kernel, dim3(1), dim3(SCAN_T), 0, stream, deg, offs, cursor, N_NODES);
    hipLaunchKernelGGL(scatter_kernel, dim3((N_EDGES + 255) / 256), dim3(256), 0, stream,
                       src, dst, cursor, csr_src, N_EDGES);

    // all weight transposes in one launch (into concatenated [Wl^T|Wr^T|Ws^T] buffers)
    {
        TransJobs jb;
        const float* Ws_[9]  = {Wl1, Wr1, Ws1, Wl2, Wr2, Ws2, Wl3, Wr3, Ws3};
        unsigned short* Wt_[9] = {Wcat1, Wcat1 + 512 * 256, Wcat1 + 2 * 512 * 256,
                                  Wcat2, Wcat2 + 256 * 512, Wcat2 + 2 * 256 * 512,
                                  Wcat3, Wcat3 + 128 * 256, Wcat3 + 2 * 128 * 256};
        int K_[9] = {256, 256, 256, 512, 512, 512, 256, 256, 256};
        int D_[9] = {512, 512, 512, 256, 256, 256, 128, 128, 128};
        int o = 0;
        for (int i = 0; i < 9; ++i) {
            jb.W[i] = Ws_[i]; jb.Wt[i] = Wt_[i]; jb.K[i] = K_[i]; jb.D[i] = D_[i];
            jb.beg[i] = o; o += K_[i] * D_[i];
        }
        jb.beg[9] = o;
        hipLaunchKernelGGL(transpose_all_kernel, dim3((o + 255) / 256), dim3(256), 0, stream, jb);
    }

    // x -> bf16
    {
        int nconv = N_NODES * 256;
        hipLaunchKernelGGL(convert_bf16_kernel, dim3((nconv / 4 + 255) / 256), dim3(256), 0, stream,
                           x, xbf, nconv);
    }

    // layer 1: 256 -> 512, relu, bf16 out
    run_layer(xbf, 256, 512, Wcat1, att1, bc1, bs1,
              xlb, xrb, seedb, (float*)nullptr, offs, csr_src,
              (float*)nullptr, h1b, 0, stream);
    // layer 2: 512 -> 256, relu, bf16 out
    run_layer(h1b, 512, 256, Wcat2, att2, bc2, bs2,
              xlb, xrb, seedb, (float*)nullptr, offs, csr_src,
              (float*)nullptr, h2b, 0, stream);
    // layer 3: 256 -> 128, no relu, fp32 out; seed directly in d_out
    run_layer(h2b, 256, 128, Wcat3, att3, bc3, bs3,
              xlb, xrb, (unsigned short*)nullptr, (float*)d_out, offs, csr_src,
              (float*)d_out, (unsigned short*)nullptr, 1, stream);
}

// Round 5
// 422.674 us; speedup vs baseline: 2.8317x; 1.0407x over previous
//
#include <hip/hip_runtime.h>
#include <hip/hip_bf16.h>
#include <math.h>

#define N_NODES 20000
#define N_EDGES 320000

typedef __bf16 bf16x8 __attribute__((ext_vector_type(8)));
typedef float f32x4 __attribute__((ext_vector_type(4)));

__device__ __forceinline__ unsigned short f2bf(float f) {
    unsigned int u = __float_as_uint(f);
    unsigned int r = u + 0x7FFFu + ((u >> 16) & 1u);   // round-to-nearest-even
    return (unsigned short)(r >> 16);
}

// ---------------------------------------------------------------------------
// CSR build
// ---------------------------------------------------------------------------
__global__ void zero_int_kernel(int* __restrict__ p, int n) {
    int i = blockIdx.x * blockDim.x + threadIdx.x;
    if (i < n) p[i] = 0;
}

__global__ void count_deg_kernel(const int* __restrict__ dst, int* __restrict__ deg, int E) {
    int i = blockIdx.x * blockDim.x + threadIdx.x;
    if (i < E) atomicAdd(&deg[dst[i]], 1);
}

// single-pass scan: thread t serially scans its 20-elem chunk, one LDS scan of totals
#define SCAN_T 1024
#define SCAN_C 20   // ceil(20000/1024)
__global__ __launch_bounds__(1024) void scan_kernel(const int* __restrict__ deg,
                                                    int* __restrict__ offs,
                                                    int* __restrict__ cursor, int n) {
    __shared__ int sd[SCAN_T];
    int t = threadIdx.x;
    int base = t * SCAN_C;
    int vex[SCAN_C];
    int run = 0;
#pragma unroll
    for (int k = 0; k < SCAN_C; ++k) {
        int i = base + k;
        int d = (i < n) ? deg[i] : 0;
        vex[k] = run;          // local exclusive prefix
        run += d;
    }
    sd[t] = run;
    __syncthreads();
    for (int off = 1; off < SCAN_T; off <<= 1) {
        int x = (t >= off) ? sd[t - off] : 0;
        __syncthreads();
        sd[t] += x;
        __syncthreads();
    }
    int excl = sd[t] - run;
#pragma unroll
    for (int k = 0; k < SCAN_C; ++k) {
        int i = base + k;
        if (i < n) { int e = excl + vex[k]; offs[i] = e; cursor[i] = e; }
    }
    if (t == SCAN_T - 1) offs[n] = sd[t];
}

__global__ void scatter_kernel(const int* __restrict__ src, const int* __restrict__ dst,
                               int* __restrict__ cursor, int* __restrict__ csr_src, int E) {
    int i = blockIdx.x * blockDim.x + threadIdx.x;
    if (i < E) {
        int pos = atomicAdd(&cursor[dst[i]], 1);
        csr_src[pos] = src[i];
    }
}

// ---------------------------------------------------------------------------
// conversions
// ---------------------------------------------------------------------------
__global__ void convert_bf16_kernel(const float* __restrict__ in,
                                    unsigned short* __restrict__ out, int n) {
    int i = blockIdx.x * blockDim.x + threadIdx.x;
    int base = i * 4;
    if (base + 3 < n) {
        float4 v = *(const float4*)(in + base);
        out[base + 0] = f2bf(v.x);
        out[base + 1] = f2bf(v.y);
        out[base + 2] = f2bf(v.z);
        out[base + 3] = f2bf(v.w);
    } else {
        for (int k = base; k < n; ++k) out[k] = f2bf(in[k]);
    }
}

// all 9 weight transposes (fp32 [K][D] -> bf16 [D][K]) in one launch
struct TransJobs {
    const float* W[9];
    unsigned short* Wt[9];
    int K[9];
    int D[9];
    int beg[10];
};
__global__ void transpose_all_kernel(TransJobs jb) {
    int i = blockIdx.x * blockDim.x + threadIdx.x;
    if (i >= jb.beg[9]) return;
    int job = 0;
    while (i >= jb.beg[job + 1]) ++job;
    int local = i - jb.beg[job];
    int D = jb.D[job], K = jb.K[job];
    int k = local / D, d = local - k * D;
    jb.Wt[job][(size_t)d * K + k] = f2bf(jb.W[job][local]);
}

// ---------------------------------------------------------------------------
// fused 3-in-1 bf16 MFMA GEMM:
//   [xl | xr | seed] = A[M,K] @ Btcat[3D,K]^T  (bias bs+bc on seed segment)
// 128x128 tile, BK=64, 256 threads = 4 waves of 64x64, 16x16x32 MFMA.
// OPERANDS SWAPPED vs the naive form: mfma(Bt_frag, A_frag) so each lane holds
// 4 CONSECUTIVE output columns (n = q*4+reg) at a fixed row (m = t), enabling
// packed 8B bf16 / 16B fp32 epilogue stores (kills 2x sector write-amp).
// ---------------------------------------------------------------------------
#define GBK 64
#define LDK 72  // padded k-stride (bf16 elems)

template <int SEED_F32>
__global__ __launch_bounds__(256) void gemm3_kernel(
        const unsigned short* __restrict__ A,    // [M][K] bf16
        const unsigned short* __restrict__ Bt,   // [3D][K] bf16 (Wl^T|Wr^T|Ws^T)
        unsigned short* __restrict__ xlb,        // [M][D] bf16
        unsigned short* __restrict__ xrb,        // [M][D] bf16
        unsigned short* __restrict__ seedb,      // [M][D] bf16 (SEED_F32==0)
        float* __restrict__ seedf,               // [M][D] fp32 (SEED_F32==1)
        const float* __restrict__ b1,
        const float* __restrict__ b2,
        int M, int K, int D) {
    __shared__ __align__(16) unsigned short Asl[128 * LDK];
    __shared__ __align__(16) unsigned short Bsl[128 * LDK];

    int tid = threadIdx.x;
    int wave = tid >> 6, lane = tid & 63;
    int q = lane >> 4, t = lane & 15;
    int wm = (wave & 1) * 64, wn = (wave >> 1) * 64;
    int bm = blockIdx.y * 128;
    int bn_all = blockIdx.x * 128;
    int seg = bn_all / D;            // D is a multiple of 128 -> block-uniform
    int bn = bn_all - seg * D;

    // acc[jn][im]: value reg r at lane (q,t) = C[m = im*16 + t][n = jn*16 + q*4 + r]
    f32x4 acc[4][4];
#pragma unroll
    for (int i = 0; i < 4; ++i)
#pragma unroll
        for (int j = 0; j < 4; ++j) acc[i][j] = (f32x4){0.f, 0.f, 0.f, 0.f};

    for (int k0 = 0; k0 < K; k0 += GBK) {
        // stage A tile: 128 rows x 64 k = 1024 16B chunks, 4 per thread
#pragma unroll
        for (int c = tid; c < 1024; c += 256) {
            int row = c >> 3, part = c & 7;
            int gr = bm + row; if (gr >= M) gr = M - 1;   // clamp (rows >= M discarded)
            uint4 val = *(const uint4*)(A + (size_t)gr * K + k0 + part * 8);
            *(uint4*)(Asl + row * LDK + part * 8) = val;
        }
        // stage Bt tile (3D is a multiple of 128 -> no guard)
#pragma unroll
        for (int c = tid; c < 1024; c += 256) {
            int row = c >> 3, part = c & 7;
            uint4 val = *(const uint4*)(Bt + (size_t)(bn_all + row) * K + k0 + part * 8);
            *(uint4*)(Bsl + row * LDK + part * 8) = val;
        }
        __syncthreads();

#pragma unroll
        for (int h = 0; h < 2; ++h) {   // two K=32 halves of the BK=64 tile
            bf16x8 an[4], am[4];
#pragma unroll
            for (int jn = 0; jn < 4; ++jn)
                an[jn] = *(const bf16x8*)(Bsl + (wn + jn * 16 + t) * LDK + h * 32 + q * 8);
#pragma unroll
            for (int im = 0; im < 4; ++im)
                am[im] = *(const bf16x8*)(Asl + (wm + im * 16 + t) * LDK + h * 32 + q * 8);
#pragma unroll
            for (int jn = 0; jn < 4; ++jn)
#pragma unroll
                for (int im = 0; im < 4; ++im)
                    acc[jn][im] = __builtin_amdgcn_mfma_f32_16x16x32_bf16(an[jn], am[im], acc[jn][im], 0, 0, 0);
        }
        __syncthreads();
    }

    // epilogue: per lane, 4 consecutive columns per (jn,im) -> packed stores
#pragma unroll
    for (int jn = 0; jn < 4; ++jn) {
        int n0 = bn + wn + jn * 16 + q * 4;
        float bx = 0.f, by = 0.f, bz = 0.f, bw = 0.f;
        if (seg == 2) {
            float4 bb1 = *(const float4*)(b1 + n0);
            float4 bb2 = *(const float4*)(b2 + n0);
            bx = bb1.x + bb2.x; by = bb1.y + bb2.y;
            bz = bb1.z + bb2.z; bw = bb1.w + bb2.w;
        }
#pragma unroll
        for (int im = 0; im < 4; ++im) {
            int m = bm + wm + im * 16 + t;
            if (m < M) {
                float v0 = acc[jn][im][0] + bx;
                float v1 = acc[jn][im][1] + by;
                float v2 = acc[jn][im][2] + bz;
                float v3 = acc[jn][im][3] + bw;
                size_t idx = (size_t)m * D + n0;
                if (seg == 2 && SEED_F32) {
                    *(float4*)(seedf + idx) = make_float4(v0, v1, v2, v3);
                } else {
                    uint2 pk;
                    pk.x = (unsigned int)f2bf(v0) | ((unsigned int)f2bf(v1) << 16);
                    pk.y = (unsigned int)f2bf(v2) | ((unsigned int)f2bf(v3) << 16);
                    unsigned short* dstp = (seg == 0) ? xlb : (seg == 1) ? xrb : seedb;
                    *(uint2*)(dstp + idx) = pk;
                }
            }
        }
    }
}

// ---------------------------------------------------------------------------
// fused per-node: edge scores + online softmax + aggregation + skip.
// One 64-lane wave per destination node, 2 edges per iteration (ILP),
// always-rescale online softmax (exp(-inf)=0 handles init).
// ---------------------------------------------------------------------------
template <int D, int SEED_BF, int WRITE_BF, int RELU>
__global__ __launch_bounds__(256) void fused_agg_kernel(
        const unsigned short* __restrict__ xl,
        const unsigned short* __restrict__ xr,
        const float* __restrict__ att,
        const int* __restrict__ offs,
        const int* __restrict__ csr_src,
        const unsigned short* __restrict__ seedb,
        const float* __restrict__ seedf,
        float* __restrict__ outf,
        unsigned short* __restrict__ outb) {
    constexpr int VPL = D / 64;
    typedef __bf16 bvec __attribute__((ext_vector_type(VPL)));

    int wave = threadIdx.x >> 6, lane = threadIdx.x & 63;
    int n = blockIdx.x * 4 + wave;
    if (n >= N_NODES) return;
    int beg = offs[n], end = offs[n + 1];

    float xr_f[VPL], att_f[VPL];
    bvec xrv = *(const bvec*)(xr + (size_t)n * D + lane * VPL);
#pragma unroll
    for (int v = 0; v < VPL; ++v) {
        xr_f[v] = (float)xrv[v];
        att_f[v] = att[lane * VPL + v];
    }

    float acc[VPL];
#pragma unroll
    for (int v = 0; v < VPL; ++v) acc[v] = 0.f;
    float m = -INFINITY, s = 0.f;

    int j = beg;
    for (; j + 1 < end; j += 2) {
        int s0 = csr_src[j], s1 = csr_src[j + 1];
        bvec xv0 = *(const bvec*)(xl + (size_t)s0 * D + lane * VPL);
        bvec xv1 = *(const bvec*)(xl + (size_t)s1 * D + lane * VPL);
        float xf0[VPL], xf1[VPL];
        float p0 = 0.f, p1 = 0.f;
#pragma unroll
        for (int v = 0; v < VPL; ++v) {
            xf0[v] = (float)xv0[v];
            xf1[v] = (float)xv1[v];
            float t0 = xf0[v] + xr_f[v];
            float t1 = xf1[v] + xr_f[v];
            t0 = fmaxf(t0, 0.2f * t0);      // leaky_relu(t) == max(t, 0.2t)
            t1 = fmaxf(t1, 0.2f * t1);
            p0 += t0 * att_f[v];
            p1 += t1 * att_f[v];
        }
#pragma unroll
        for (int o = 32; o > 0; o >>= 1) {   // two interleaved allreduce chains
            p0 += __shfl_xor(p0, o, 64);
            p1 += __shfl_xor(p1, o, 64);
        }
        float mn = fmaxf(m, fmaxf(p0, p1));
        float sc = __expf(m - mn);           // first iter: exp(-inf)=0
        float e0 = __expf(p0 - mn);
        float e1 = __expf(p1 - mn);
        s = s * sc + e0 + e1;
#pragma unroll
        for (int v = 0; v < VPL; ++v)
            acc[v] = acc[v] * sc + e0 * xf0[v] + e1 * xf1[v];
        m = mn;
    }
    if (j < end) {   // odd tail
        int s0 = csr_src[j];
        bvec xv0 = *(const bvec*)(xl + (size_t)s0 * D + lane * VPL);
        float xf0[VPL];
        float p0 = 0.f;
#pragma unroll
        for (int v = 0; v < VPL; ++v) {
            xf0[v] = (float)xv0[v];
            float t0 = xf0[v] + xr_f[v];
            t0 = fmaxf(t0, 0.2f * t0);
            p0 += t0 * att_f[v];
        }
#pragma unroll
        for (int o = 32; o > 0; o >>= 1) p0 += __shfl_xor(p0, o, 64);
        float mn = fmaxf(m, p0);
        float sc = __expf(m - mn);
        float e0 = __expf(p0 - mn);
        s = s * sc + e0;
#pragma unroll
        for (int v = 0; v < VPL; ++v) acc[v] = acc[v] * sc + e0 * xf0[v];
        m = mn;
    }

    float sinv = 1.0f / (s + 1e-16f);
    size_t base = (size_t)n * D + lane * VPL;
    float sd[VPL];
    if (SEED_BF) {
        bvec sv = *(const bvec*)(seedb + base);
#pragma unroll
        for (int v = 0; v < VPL; ++v) sd[v] = (float)sv[v];
    } else {
#pragma unroll
        for (int v = 0; v < VPL; ++v) sd[v] = seedf[base + v];
    }
#pragma unroll
    for (int v = 0; v < VPL; ++v) {
        float val = sd[v] + acc[v] * sinv;
        if (RELU) val = fmaxf(val, 0.f);
        if (WRITE_BF) outb[base + v] = f2bf(val);
        else          outf[base + v] = val;
    }
}

// ---------------------------------------------------------------------------
// host-side layer driver
// ---------------------------------------------------------------------------
static void run_layer(const unsigned short* hbf, int K, int D,
                      const unsigned short* Wcat,
                      const float* att, const float* bc, const float* bs,
                      unsigned short* xlb, unsigned short* xrb,
                      unsigned short* seedb, float* seedf,
                      const int* offs, const int* csr_src,
                      float* outf, unsigned short* outb, int final_layer,
                      hipStream_t stream) {
    dim3 ggrid(3 * D / 128, (N_NODES + 127) / 128);
    if (final_layer)
        hipLaunchKernelGGL((gemm3_kernel<1>), ggrid, dim3(256), 0, stream, hbf, Wcat,
                           xlb, xrb, (unsigned short*)nullptr, seedf, bs, bc, N_NODES, K, D);
    else
        hipLaunchKernelGGL((gemm3_kernel<0>), ggrid, dim3(256), 0, stream, hbf, Wcat,
                           xlb, xrb, seedb, (float*)nullptr, bs, bc, N_NODES, K, D);

    dim3 agrid((N_NODES + 3) / 4);
    if (D == 512) {
        hipLaunchKernelGGL((fused_agg_kernel<512, 1, 1, 1>), agrid, dim3(256), 0, stream,
                           xlb, xrb, att, offs, csr_src, seedb, (const float*)nullptr,
                           (float*)nullptr, outb);
    } else if (D == 256) {
        hipLaunchKernelGGL((fused_agg_kernel<256, 1, 1, 1>), agrid, dim3(256), 0, stream,
                           xlb, xrb, att, offs, csr_src, seedb, (const float*)nullptr,
                           (float*)nullptr, outb);
    } else {
        hipLaunchKernelGGL((fused_agg_kernel<128, 0, 0, 0>), agrid, dim3(256), 0, stream,
                           xlb, xrb, att, offs, csr_src, (const unsigned short*)nullptr, seedf,
                           outf, (unsigned short*)nullptr);
    }
}

extern "C" void kernel_launch(void* const* d_in, const int* in_sizes, int n_in,
                              void* d_out, int out_size, void* d_ws, size_t ws_size,
                              hipStream_t stream) {
    const float* x = (const float*)d_in[0];
    const int* ei = (const int*)d_in[1];
    const int* src = ei;
    const int* dst = ei + N_EDGES;

    const float* Wl1 = (const float*)d_in[2];
    const float* Wr1 = (const float*)d_in[3];
    const float* att1 = (const float*)d_in[4];
    const float* bc1 = (const float*)d_in[5];
    const float* Ws1 = (const float*)d_in[6];
    const float* bs1 = (const float*)d_in[7];
    const float* Wl2 = (const float*)d_in[8];
    const float* Wr2 = (const float*)d_in[9];
    const float* att2 = (const float*)d_in[10];
    const float* bc2 = (const float*)d_in[11];
    const float* Ws2 = (const float*)d_in[12];
    const float* bs2 = (const float*)d_in[13];
    const float* Wl3 = (const float*)d_in[14];
    const float* Wr3 = (const float*)d_in[15];
    const float* att3 = (const float*)d_in[16];
    const float* bc3 = (const float*)d_in[17];
    const float* Ws3 = (const float*)d_in[18];
    const float* bs3 = (const float*)d_in[19];

    // workspace carve
    const size_t NF = (size_t)N_NODES * 512;
    const size_t NH = (size_t)N_NODES * 256;
    unsigned short* xlb   = (unsigned short*)d_ws;      // N x 512 bf16 (reused per layer)
    unsigned short* xrb   = xlb + NF;
    unsigned short* seedb = xrb + NF;                   // N x 512 bf16 (layers 1-2)
    unsigned short* xbf   = seedb + NF;                 // x as bf16: N x 256
    unsigned short* h1b   = xbf + NH;                   // layer1 out: N x 512
    unsigned short* h2b   = h1b + NF;                   // layer2 out: N x 256
    unsigned short* Wcat1 = h2b + NH;                   // 3 x 512 x 256
    unsigned short* Wcat2 = Wcat1 + 3 * 512 * 256;      // 3 x 256 x 512
    unsigned short* Wcat3 = Wcat2 + 3 * 256 * 512;      // 3 x 128 x 256
    int* deg     = (int*)(Wcat3 + 3 * 128 * 256);
    int* offs    = deg + N_NODES;
    int* cursor  = offs + N_NODES + 1;
    int* csr_src = cursor + N_NODES;
    size_t needed = (size_t)((char*)(csr_src + N_EDGES) - (char*)d_ws);
    if (ws_size < needed) return;

    // CSR build
    hipLaunchKernelGGL(zero_int_kernel, dim3((N_NODES + 255) / 256), dim3(256), 0, stream,
                       deg, N_NODES);
    hipLaunchKernelGGL(count_deg_kernel, dim3((N_EDGES + 255) / 256), dim3(256), 0, stream,
                       dst, deg, N_EDGES);
    hipLaunchKernelGGL(scan_kernel, dim3(1), dim3(SCAN_T), 0, stream, deg, offs, cursor, N_NODES);
    hipLaunchKernelGGL(scatter_kernel, dim3((N_EDGES + 255) / 256), dim3(256), 0, stream,
                       src, dst, cursor, csr_src, N_EDGES);

    // all weight transposes in one launch (into concatenated [Wl^T|Wr^T|Ws^T] buffers)
    {
        TransJobs jb;
        const float* Ws_[9]  = {Wl1, Wr1, Ws1, Wl2, Wr2, Ws2, Wl3, Wr3, Ws3};
        unsigned short* Wt_[9] = {Wcat1, Wcat1 + 512 * 256, Wcat1 + 2 * 512 * 256,
                                  Wcat2, Wcat2 + 256 * 512, Wcat2 + 2 * 256 * 512,
                                  Wcat3, Wcat3 + 128 * 256, Wcat3 + 2 * 128 * 256};
        int K_[9] = {256, 256, 256, 512, 512, 512, 256, 256, 256};
        int D_[9] = {512, 512, 512, 256, 256, 256, 128, 128, 128};
        int o = 0;
        for (int i = 0; i < 9; ++i) {
            jb.W[i] = Ws_[i]; jb.Wt[i] = Wt_[i]; jb.K[i] = K_[i]; jb.D[i] = D_[i];
            jb.beg[i] = o; o += K_[i] * D_[i];
        }
        jb.beg[9] = o;
        hipLaunchKernelGGL(transpose_all_kernel, dim3((o + 255) / 256), dim3(256), 0, stream, jb);
    }

    // x -> bf16
    {
        int nconv = N_NODES * 256;
        hipLaunchKernelGGL(convert_bf16_kernel, dim3((nconv / 4 + 255) / 256), dim3(256), 0, stream,
                           x, xbf, nconv);
    }

    // layer 1: 256 -> 512, relu, bf16 out
    run_layer(xbf, 256, 512, Wcat1, att1, bc1, bs1,
              xlb, xrb, seedb, (float*)nullptr, offs, csr_src,
              (float*)nullptr, h1b, 0, stream);
    // layer 2: 512 -> 256, relu, bf16 out
    run_layer(h1b, 512, 256, Wcat2, att2, bc2, bs2,
              xlb, xrb, seedb, (float*)nullptr, offs, csr_src,
              (float*)nullptr, h2b, 0, stream);
    // layer 3: 256 -> 128, no relu, fp32 out; seed directly in d_out
    run_layer(h2b, 256, 128, Wcat3, att3, bc3, bs3,
              xlb, xrb, (unsigned short*)nullptr, (float*)d_out, offs, csr_src,
              (float*)d_out, (unsigned short*)nullptr, 1, stream);
}

// Round 6
// 392.685 us; speedup vs baseline: 3.0480x; 1.0764x over previous
//
#include <hip/hip_runtime.h>
#include <hip/hip_bf16.h>
#include <math.h>

#define N_NODES 20000
#define N_EDGES 320000

typedef __bf16 bf16x8 __attribute__((ext_vector_type(8)));
typedef float f32x4 __attribute__((ext_vector_type(4)));

__device__ __forceinline__ unsigned short f2bf(float f) {
    unsigned int u = __float_as_uint(f);
    unsigned int r = u + 0x7FFFu + ((u >> 16) & 1u);   // round-to-nearest-even
    return (unsigned short)(r >> 16);
}

// async global->LDS DMA, 16B per lane; LDS dest = wave-uniform base + lane*16
typedef const unsigned int __attribute__((address_space(1)))* gas_ptr;
typedef unsigned int __attribute__((address_space(3)))* las_ptr;
__device__ __forceinline__ void gld16(const unsigned short* g, unsigned short* l) {
    __builtin_amdgcn_global_load_lds((gas_ptr)(const void*)g, (las_ptr)(void*)l, 16, 0, 0);
}

// ---------------------------------------------------------------------------
// CSR build
// ---------------------------------------------------------------------------
__global__ void zero_int_kernel(int* __restrict__ p, int n) {
    int i = blockIdx.x * blockDim.x + threadIdx.x;
    if (i < n) p[i] = 0;
}

__global__ void count_deg_kernel(const int* __restrict__ dst, int* __restrict__ deg, int E) {
    int i = blockIdx.x * blockDim.x + threadIdx.x;
    if (i < E) atomicAdd(&deg[dst[i]], 1);
}

// single-pass scan: thread t serially scans its 20-elem chunk, one LDS scan of totals
#define SCAN_T 1024
#define SCAN_C 20   // ceil(20000/1024)
__global__ __launch_bounds__(1024) void scan_kernel(const int* __restrict__ deg,
                                                    int* __restrict__ offs,
                                                    int* __restrict__ cursor, int n) {
    __shared__ int sd[SCAN_T];
    int t = threadIdx.x;
    int base = t * SCAN_C;
    int vex[SCAN_C];
    int run = 0;
#pragma unroll
    for (int k = 0; k < SCAN_C; ++k) {
        int i = base + k;
        int d = (i < n) ? deg[i] : 0;
        vex[k] = run;          // local exclusive prefix
        run += d;
    }
    sd[t] = run;
    __syncthreads();
    for (int off = 1; off < SCAN_T; off <<= 1) {
        int x = (t >= off) ? sd[t - off] : 0;
        __syncthreads();
        sd[t] += x;
        __syncthreads();
    }
    int excl = sd[t] - run;
#pragma unroll
    for (int k = 0; k < SCAN_C; ++k) {
        int i = base + k;
        if (i < n) { int e = excl + vex[k]; offs[i] = e; cursor[i] = e; }
    }
    if (t == SCAN_T - 1) offs[n] = sd[t];
}

__global__ void scatter_kernel(const int* __restrict__ src, const int* __restrict__ dst,
                               int* __restrict__ cursor, int* __restrict__ csr_src, int E) {
    int i = blockIdx.x * blockDim.x + threadIdx.x;
    if (i < E) {
        int pos = atomicAdd(&cursor[dst[i]], 1);
        csr_src[pos] = src[i];
    }
}

// ---------------------------------------------------------------------------
// conversions
// ---------------------------------------------------------------------------
__global__ void convert_bf16_kernel(const float* __restrict__ in,
                                    unsigned short* __restrict__ out, int n) {
    int i = blockIdx.x * blockDim.x + threadIdx.x;
    int base = i * 4;
    if (base + 3 < n) {
        float4 v = *(const float4*)(in + base);
        out[base + 0] = f2bf(v.x);
        out[base + 1] = f2bf(v.y);
        out[base + 2] = f2bf(v.z);
        out[base + 3] = f2bf(v.w);
    } else {
        for (int k = base; k < n; ++k) out[k] = f2bf(in[k]);
    }
}

// all 9 weight transposes (fp32 [K][D] -> bf16 [D][K]) in one launch.
// Iteration is OUTPUT-major: consecutive threads write consecutive bf16
// (coalesced); the strided fp32 reads hit L2 (weights are small + reused).
struct TransJobs {
    const float* W[9];
    unsigned short* Wt[9];
    int K[9];
    int D[9];
    int beg[10];
};
__global__ void transpose_all_kernel(TransJobs jb) {
    int i = blockIdx.x * blockDim.x + threadIdx.x;
    if (i >= jb.beg[9]) return;
    int job = 0;
    while (i >= jb.beg[job + 1]) ++job;
    int local = i - jb.beg[job];
    int D = jb.D[job], K = jb.K[job];
    int d = local / K, k = local - d * K;
    jb.Wt[job][local] = f2bf(jb.W[job][(size_t)k * D + d]);
}

// ---------------------------------------------------------------------------
// fused 3-in-1 bf16 MFMA GEMM (m97 structure):
//   [xl | xr | seed] = A[M,K] @ Btcat[3D,K]^T  (bias bs+bc on seed segment)
// 128x128 tile, BK=32, 256 threads = 4 waves of 64x64, 16x16x32 MFMA.
// Staging via global_load_lds width=16 into UNPADDED [128][32] LDS tiles
// (DMA writes wave-uniform base + lane*16 -> layout must equal chunk order).
// Operands swapped: mfma(Bt_frag, A_frag) -> lane holds 4 consecutive output
// columns (n = q*4+reg) at fixed row (m = t) -> packed 8B/16B epilogue stores.
// ---------------------------------------------------------------------------
template <int SEED_F32>
__global__ __launch_bounds__(256) void gemm3_kernel(
        const unsigned short* __restrict__ A,    // [M][K] bf16
        const unsigned short* __restrict__ Bt,   // [3D][K] bf16 (Wl^T|Wr^T|Ws^T)
        unsigned short* __restrict__ xlb,        // [M][D] bf16
        unsigned short* __restrict__ xrb,        // [M][D] bf16
        unsigned short* __restrict__ seedb,      // [M][D] bf16 (SEED_F32==0)
        float* __restrict__ seedf,               // [M][D] fp32 (SEED_F32==1)
        const float* __restrict__ b1,
        const float* __restrict__ b2,
        int M, int K, int D) {
    __shared__ __align__(16) unsigned short Asl[128 * 32];
    __shared__ __align__(16) unsigned short Bsl[128 * 32];

    int tid = threadIdx.x;
    int wave = tid >> 6, lane = tid & 63;
    int q = lane >> 4, t = lane & 15;
    int wm = (wave & 1) * 64, wn = (wave >> 1) * 64;
    int bm = blockIdx.y * 128;
    int bn_all = blockIdx.x * 128;
    int seg = bn_all / D;            // D is a multiple of 128 -> block-uniform
    int bn = bn_all - seg * D;

    // acc[jn][im]: value reg r at lane (q,t) = C[m = im*16 + t][n = jn*16 + q*4 + r]
    f32x4 acc[4][4];
#pragma unroll
    for (int i = 0; i < 4; ++i)
#pragma unroll
        for (int j = 0; j < 4; ++j) acc[i][j] = (f32x4){0.f, 0.f, 0.f, 0.f};

    for (int k0 = 0; k0 < K; k0 += 32) {
        // A tile: 128 rows x 32 k = 512 16B chunks; 256 lanes -> 2 DMA rounds
#pragma unroll
        for (int rnd = 0; rnd < 2; ++rnd) {
            int c = rnd * 256 + tid;             // per-lane chunk id
            int row = c >> 2, part = c & 3;
            int gr = bm + row; if (gr >= M) gr = M - 1;   // clamp, rows>=M unused
            gld16(A + (size_t)gr * K + k0 + part * 8,
                  Asl + (rnd * 256 + wave * 64) * 8);     // wave-uniform base
        }
        // Bt tile (3D multiple of 128 -> no guard)
#pragma unroll
        for (int rnd = 0; rnd < 2; ++rnd) {
            int c = rnd * 256 + tid;
            int row = c >> 2, part = c & 3;
            gld16(Bt + (size_t)(bn_all + row) * K + k0 + part * 8,
                  Bsl + (rnd * 256 + wave * 64) * 8);
        }
        __syncthreads();   // drains vmcnt -> DMA complete

        bf16x8 an[4], am[4];
#pragma unroll
        for (int jn = 0; jn < 4; ++jn)
            an[jn] = *(const bf16x8*)(Bsl + (wn + jn * 16 + t) * 32 + q * 8);
#pragma unroll
        for (int im = 0; im < 4; ++im)
            am[im] = *(const bf16x8*)(Asl + (wm + im * 16 + t) * 32 + q * 8);
#pragma unroll
        for (int jn = 0; jn < 4; ++jn)
#pragma unroll
            for (int im = 0; im < 4; ++im)
                acc[jn][im] = __builtin_amdgcn_mfma_f32_16x16x32_bf16(an[jn], am[im], acc[jn][im], 0, 0, 0);
        __syncthreads();   // protect LDS before next staging
    }

    // epilogue: per lane, 4 consecutive columns per (jn,im) -> packed stores
#pragma unroll
    for (int jn = 0; jn < 4; ++jn) {
        int n0 = bn + wn + jn * 16 + q * 4;
        float bx = 0.f, by = 0.f, bz = 0.f, bw = 0.f;
        if (seg == 2) {
            float4 bb1 = *(const float4*)(b1 + n0);
            float4 bb2 = *(const float4*)(b2 + n0);
            bx = bb1.x + bb2.x; by = bb1.y + bb2.y;
            bz = bb1.z + bb2.z; bw = bb1.w + bb2.w;
        }
#pragma unroll
        for (int im = 0; im < 4; ++im) {
            int m = bm + wm + im * 16 + t;
            if (m < M) {
                float v0 = acc[jn][im][0] + bx;
                float v1 = acc[jn][im][1] + by;
                float v2 = acc[jn][im][2] + bz;
                float v3 = acc[jn][im][3] + bw;
                size_t idx = (size_t)m * D + n0;
                if (seg == 2 && SEED_F32) {
                    *(float4*)(seedf + idx) = make_float4(v0, v1, v2, v3);
                } else {
                    uint2 pk;
                    pk.x = (unsigned int)f2bf(v0) | ((unsigned int)f2bf(v1) << 16);
                    pk.y = (unsigned int)f2bf(v2) | ((unsigned int)f2bf(v3) << 16);
                    unsigned short* dstp = (seg == 0) ? xlb : (seg == 1) ? xrb : seedb;
                    *(uint2*)(dstp + idx) = pk;
                }
            }
        }
    }
}

// ---------------------------------------------------------------------------
// fused per-node: edge scores + online softmax + aggregation + skip.
// One 64-lane wave per destination node, 2 edges per iteration (ILP),
// always-rescale online softmax (exp(-inf)=0 handles init).
// ---------------------------------------------------------------------------
template <int D, int SEED_BF, int WRITE_BF, int RELU>
__global__ __launch_bounds__(256) void fused_agg_kernel(
        const unsigned short* __restrict__ xl,
        const unsigned short* __restrict__ xr,
        const float* __restrict__ att,
        const int* __restrict__ offs,
        const int* __restrict__ csr_src,
        const unsigned short* __restrict__ seedb,
        const float* __restrict__ seedf,
        float* __restrict__ outf,
        unsigned short* __restrict__ outb) {
    constexpr int VPL = D / 64;
    typedef __bf16 bvec __attribute__((ext_vector_type(VPL)));

    int wave = threadIdx.x >> 6, lane = threadIdx.x & 63;
    int n = blockIdx.x * 4 + wave;
    if (n >= N_NODES) return;
    int beg = offs[n], end = offs[n + 1];

    float xr_f[VPL], att_f[VPL];
    bvec xrv = *(const bvec*)(xr + (size_t)n * D + lane * VPL);
#pragma unroll
    for (int v = 0; v < VPL; ++v) {
        xr_f[v] = (float)xrv[v];
        att_f[v] = att[lane * VPL + v];
    }

    float acc[VPL];
#pragma unroll
    for (int v = 0; v < VPL; ++v) acc[v] = 0.f;
    float m = -INFINITY, s = 0.f;

    int j = beg;
    for (; j + 1 < end; j += 2) {
        int s0 = csr_src[j], s1 = csr_src[j + 1];
        bvec xv0 = *(const bvec*)(xl + (size_t)s0 * D + lane * VPL);
        bvec xv1 = *(const bvec*)(xl + (size_t)s1 * D + lane * VPL);
        float xf0[VPL], xf1[VPL];
        float p0 = 0.f, p1 = 0.f;
#pragma unroll
        for (int v = 0; v < VPL; ++v) {
            xf0[v] = (float)xv0[v];
            xf1[v] = (float)xv1[v];
            float t0 = xf0[v] + xr_f[v];
            float t1 = xf1[v] + xr_f[v];
            t0 = fmaxf(t0, 0.2f * t0);      // leaky_relu(t) == max(t, 0.2t)
            t1 = fmaxf(t1, 0.2f * t1);
            p0 += t0 * att_f[v];
            p1 += t1 * att_f[v];
        }
#pragma unroll
        for (int o = 32; o > 0; o >>= 1) {   // two interleaved allreduce chains
            p0 += __shfl_xor(p0, o, 64);
            p1 += __shfl_xor(p1, o, 64);
        }
        float mn = fmaxf(m, fmaxf(p0, p1));
        float sc = __expf(m - mn);           // first iter: exp(-inf)=0
        float e0 = __expf(p0 - mn);
        float e1 = __expf(p1 - mn);
        s = s * sc + e0 + e1;
#pragma unroll
        for (int v = 0; v < VPL; ++v)
            acc[v] = acc[v] * sc + e0 * xf0[v] + e1 * xf1[v];
        m = mn;
    }
    if (j < end) {   // odd tail
        int s0 = csr_src[j];
        bvec xv0 = *(const bvec*)(xl + (size_t)s0 * D + lane * VPL);
        float xf0[VPL];
        float p0 = 0.f;
#pragma unroll
        for (int v = 0; v < VPL; ++v) {
            xf0[v] = (float)xv0[v];
            float t0 = xf0[v] + xr_f[v];
            t0 = fmaxf(t0, 0.2f * t0);
            p0 += t0 * att_f[v];
        }
#pragma unroll
        for (int o = 32; o > 0; o >>= 1) p0 += __shfl_xor(p0, o, 64);
        float mn = fmaxf(m, p0);
        float sc = __expf(m - mn);
        float e0 = __expf(p0 - mn);
        s = s * sc + e0;
#pragma unroll
        for (int v = 0; v < VPL; ++v) acc[v] = acc[v] * sc + e0 * xf0[v];
        m = mn;
    }

    float sinv = 1.0f / (s + 1e-16f);
    size_t base = (size_t)n * D + lane * VPL;
    float sd[VPL];
    if (SEED_BF) {
        bvec sv = *(const bvec*)(seedb + base);
#pragma unroll
        for (int v = 0; v < VPL; ++v) sd[v] = (float)sv[v];
    } else {
#pragma unroll
        for (int v = 0; v < VPL; ++v) sd[v] = seedf[base + v];
    }
#pragma unroll
    for (int v = 0; v < VPL; ++v) {
        float val = sd[v] + acc[v] * sinv;
        if (RELU) val = fmaxf(val, 0.f);
        if (WRITE_BF) outb[base + v] = f2bf(val);
        else          outf[base + v] = val;
    }
}

// ---------------------------------------------------------------------------
// host-side layer driver
// ---------------------------------------------------------------------------
static void run_layer(const unsigned short* hbf, int K, int D,
                      const unsigned short* Wcat,
                      const float* att, const float* bc, const float* bs,
                      unsigned short* xlb, unsigned short* xrb,
                      unsigned short* seedb, float* seedf,
                      const int* offs, const int* csr_src,
                      float* outf, unsigned short* outb, int final_layer,
                      hipStream_t stream) {
    dim3 ggrid(3 * D / 128, (N_NODES + 127) / 128);
    if (final_layer)
        hipLaunchKernelGGL((gemm3_kernel<1>), ggrid, dim3(256), 0, stream, hbf, Wcat,
                           xlb, xrb, (unsigned short*)nullptr, seedf, bs, bc, N_NODES, K, D);
    else
        hipLaunchKernelGGL((gemm3_kernel<0>), ggrid, dim3(256), 0, stream, hbf, Wcat,
                           xlb, xrb, seedb, (float*)nullptr, bs, bc, N_NODES, K, D);

    dim3 agrid((N_NODES + 3) / 4);
    if (D == 512) {
        hipLaunchKernelGGL((fused_agg_kernel<512, 1, 1, 1>), agrid, dim3(256), 0, stream,
                           xlb, xrb, att, offs, csr_src, seedb, (const float*)nullptr,
                           (float*)nullptr, outb);
    } else if (D == 256) {
        hipLaunchKernelGGL((fused_agg_kernel<256, 1, 1, 1>), agrid, dim3(256), 0, stream,
                           xlb, xrb, att, offs, csr_src, seedb, (const float*)nullptr,
                           (float*)nullptr, outb);
    } else {
        hipLaunchKernelGGL((fused_agg_kernel<128, 0, 0, 0>), agrid, dim3(256), 0, stream,
                           xlb, xrb, att, offs, csr_src, (const unsigned short*)nullptr, seedf,
                           outf, (unsigned short*)nullptr);
    }
}

extern "C" void kernel_launch(void* const* d_in, const int* in_sizes, int n_in,
                              void* d_out, int out_size, void* d_ws, size_t ws_size,
                              hipStream_t stream) {
    const float* x = (const float*)d_in[0];
    const int* ei = (const int*)d_in[1];
    const int* src = ei;
    const int* dst = ei + N_EDGES;

    const float* Wl1 = (const float*)d_in[2];
    const float* Wr1 = (const float*)d_in[3];
    const float* att1 = (const float*)d_in[4];
    const float* bc1 = (const float*)d_in[5];
    const float* Ws1 = (const float*)d_in[6];
    const float* bs1 = (const float*)d_in[7];
    const float* Wl2 = (const float*)d_in[8];
    const float* Wr2 = (const float*)d_in[9];
    const float* att2 = (const float*)d_in[10];
    const float* bc2 = (const float*)d_in[11];
    const float* Ws2 = (const float*)d_in[12];
    const float* bs2 = (const float*)d_in[13];
    const float* Wl3 = (const float*)d_in[14];
    const float* Wr3 = (const float*)d_in[15];
    const float* att3 = (const float*)d_in[16];
    const float* bc3 = (const float*)d_in[17];
    const float* Ws3 = (const float*)d_in[18];
    const float* bs3 = (const float*)d_in[19];

    // workspace carve
    const size_t NF = (size_t)N_NODES * 512;
    const size_t NH = (size_t)N_NODES * 256;
    unsigned short* xlb   = (unsigned short*)d_ws;      // N x 512 bf16 (reused per layer)
    unsigned short* xrb   = xlb + NF;
    unsigned short* seedb = xrb + NF;                   // N x 512 bf16 (layers 1-2)
    unsigned short* xbf   = seedb + NF;                 // x as bf16: N x 256
    unsigned short* h1b   = xbf + NH;                   // layer1 out: N x 512
    unsigned short* h2b   = h1b + NF;                   // layer2 out: N x 256
    unsigned short* Wcat1 = h2b + NH;                   // 3 x 512 x 256
    unsigned short* Wcat2 = Wcat1 + 3 * 512 * 256;      // 3 x 256 x 512
    unsigned short* Wcat3 = Wcat2 + 3 * 256 * 512;      // 3 x 128 x 256
    int* deg     = (int*)(Wcat3 + 3 * 128 * 256);
    int* offs    = deg + N_NODES;
    int* cursor  = offs + N_NODES + 1;
    int* csr_src = cursor + N_NODES;
    size_t needed = (size_t)((char*)(csr_src + N_EDGES) - (char*)d_ws);
    if (ws_size < needed) return;

    // CSR build
    hipLaunchKernelGGL(zero_int_kernel, dim3((N_NODES + 255) / 256), dim3(256), 0, stream,
                       deg, N_NODES);
    hipLaunchKernelGGL(count_deg_kernel, dim3((N_EDGES + 255) / 256), dim3(256), 0, stream,
                       dst, deg, N_EDGES);
    hipLaunchKernelGGL(scan_kernel, dim3(1), dim3(SCAN_T), 0, stream, deg, offs, cursor, N_NODES);
    hipLaunchKernelGGL(scatter_kernel, dim3((N_EDGES + 255) / 256), dim3(256), 0, stream,
                       src, dst, cursor, csr_src, N_EDGES);

    // all weight transposes in one launch (into concatenated [Wl^T|Wr^T|Ws^T] buffers)
    {
        TransJobs jb;
        const float* Ws_[9]  = {Wl1, Wr1, Ws1, Wl2, Wr2, Ws2, Wl3, Wr3, Ws3};
        unsigned short* Wt_[9] = {Wcat1, Wcat1 + 512 * 256, Wcat1 + 2 * 512 * 256,
                                  Wcat2, Wcat2 + 256 * 512, Wcat2 + 2 * 256 * 512,
                                  Wcat3, Wcat3 + 128 * 256, Wcat3 + 2 * 128 * 256};
        int K_[9] = {256, 256, 256, 512, 512, 512, 256, 256, 256};
        int D_[9] = {512, 512, 512, 256, 256, 256, 128, 128, 128};
        int o = 0;
        for (int i = 0; i < 9; ++i) {
            jb.W[i] = Ws_[i]; jb.Wt[i] = Wt_[i]; jb.K[i] = K_[i]; jb.D[i] = D_[i];
            jb.beg[i] = o; o += K_[i] * D_[i];
        }
        jb.beg[9] = o;
        hipLaunchKernelGGL(transpose_all_kernel, dim3((o + 255) / 256), dim3(256), 0, stream, jb);
    }

    // x -> bf16
    {
        int nconv = N_NODES * 256;
        hipLaunchKernelGGL(convert_bf16_kernel, dim3((nconv / 4 + 255) / 256), dim3(256), 0, stream,
                           x, xbf, nconv);
    }

    // layer 1: 256 -> 512, relu, bf16 out
    run_layer(xbf, 256, 512, Wcat1, att1, bc1, bs1,
              xlb, xrb, seedb, (float*)nullptr, offs, csr_src,
              (float*)nullptr, h1b, 0, stream);
    // layer 2: 512 -> 256, relu, bf16 out
    run_layer(h1b, 512, 256, Wcat2, att2, bc2, bs2,
              xlb, xrb, seedb, (float*)nullptr, offs, csr_src,
              (float*)nullptr, h2b, 0, stream);
    // layer 3: 256 -> 128, no relu, fp32 out; seed directly in d_out
    run_layer(h2b, 256, 128, Wcat3, att3, bc3, bs3,
              xlb, xrb, (unsigned short*)nullptr, (float*)d_out, offs, csr_src,
              (float*)d_out, (unsigned short*)nullptr, 1, stream);
}

// Round 7
// 375.114 us; speedup vs baseline: 3.1908x; 1.0468x over previous
//
#include <hip/hip_runtime.h>
#include <hip/hip_bf16.h>
#include <math.h>

#define N_NODES 20000
#define N_EDGES 320000

typedef __bf16 bf16x8 __attribute__((ext_vector_type(8)));
typedef float f32x4 __attribute__((ext_vector_type(4)));

__device__ __forceinline__ unsigned short f2bf(float f) {
    unsigned int u = __float_as_uint(f);
    unsigned int r = u + 0x7FFFu + ((u >> 16) & 1u);   // round-to-nearest-even
    return (unsigned short)(r >> 16);
}

// async global->LDS DMA, 16B per lane; LDS dest = wave-uniform base + lane*16
typedef const unsigned int __attribute__((address_space(1)))* gas_ptr;
typedef unsigned int __attribute__((address_space(3)))* las_ptr;
__device__ __forceinline__ void gld16(const unsigned short* g, unsigned short* l) {
    __builtin_amdgcn_global_load_lds((gas_ptr)(const void*)g, (las_ptr)(void*)l, 16, 0, 0);
}

// ---------------------------------------------------------------------------
// CSR build
// ---------------------------------------------------------------------------
__global__ void zero_int_kernel(int* __restrict__ p, int n) {
    int i = blockIdx.x * blockDim.x + threadIdx.x;
    if (i < n) p[i] = 0;
}

__global__ void count_deg_kernel(const int* __restrict__ dst, int* __restrict__ deg, int E) {
    int i = blockIdx.x * blockDim.x + threadIdx.x;
    if (i < E) atomicAdd(&deg[dst[i]], 1);
}

// single-pass scan: thread t serially scans its 20-elem chunk, one LDS scan of totals
#define SCAN_T 1024
#define SCAN_C 20   // ceil(20000/1024)
__global__ __launch_bounds__(1024) void scan_kernel(const int* __restrict__ deg,
                                                    int* __restrict__ offs,
                                                    int* __restrict__ cursor, int n) {
    __shared__ int sd[SCAN_T];
    int t = threadIdx.x;
    int base = t * SCAN_C;
    int vex[SCAN_C];
    int run = 0;
#pragma unroll
    for (int k = 0; k < SCAN_C; ++k) {
        int i = base + k;
        int d = (i < n) ? deg[i] : 0;
        vex[k] = run;          // local exclusive prefix
        run += d;
    }
    sd[t] = run;
    __syncthreads();
    for (int off = 1; off < SCAN_T; off <<= 1) {
        int x = (t >= off) ? sd[t - off] : 0;
        __syncthreads();
        sd[t] += x;
        __syncthreads();
    }
    int excl = sd[t] - run;
#pragma unroll
    for (int k = 0; k < SCAN_C; ++k) {
        int i = base + k;
        if (i < n) { int e = excl + vex[k]; offs[i] = e; cursor[i] = e; }
    }
    if (t == SCAN_T - 1) offs[n] = sd[t];
}

__global__ void scatter_kernel(const int* __restrict__ src, const int* __restrict__ dst,
                               int* __restrict__ cursor, int* __restrict__ csr_src, int E) {
    int i = blockIdx.x * blockDim.x + threadIdx.x;
    if (i < E) {
        int pos = atomicAdd(&cursor[dst[i]], 1);
        csr_src[pos] = src[i];
    }
}

// ---------------------------------------------------------------------------
// conversions
// ---------------------------------------------------------------------------
__global__ void convert_bf16_kernel(const float* __restrict__ in,
                                    unsigned short* __restrict__ out, int n) {
    int i = blockIdx.x * blockDim.x + threadIdx.x;
    int base = i * 4;
    if (base + 3 < n) {
        float4 v = *(const float4*)(in + base);
        out[base + 0] = f2bf(v.x);
        out[base + 1] = f2bf(v.y);
        out[base + 2] = f2bf(v.z);
        out[base + 3] = f2bf(v.w);
    } else {
        for (int k = base; k < n; ++k) out[k] = f2bf(in[k]);
    }
}

// all 9 weight transposes (fp32 [K][D] -> bf16 [D][K]) in one launch.
// Output-major iteration: coalesced bf16 writes; strided fp32 reads hit L2.
struct TransJobs {
    const float* W[9];
    unsigned short* Wt[9];
    int K[9];
    int D[9];
    int beg[10];
};
__global__ void transpose_all_kernel(TransJobs jb) {
    int i = blockIdx.x * blockDim.x + threadIdx.x;
    if (i >= jb.beg[9]) return;
    int job = 0;
    while (i >= jb.beg[job + 1]) ++job;
    int local = i - jb.beg[job];
    int D = jb.D[job], K = jb.K[job];
    int d = local / K, k = local - d * K;
    jb.Wt[job][local] = f2bf(jb.W[job][(size_t)k * D + d]);
}

// ---------------------------------------------------------------------------
// fused 3-in-1 bf16 MFMA GEMM (m97 structure):
//   [xl | xr | seed] = A[M,K] @ Btcat[3D,K]^T  (bias bs+bc on seed segment)
// 128x128 tile, BK=32, 256 threads = 4 waves of 64x64, 16x16x32 MFMA.
// Staging via global_load_lds width=16 into UNPADDED [128][32] LDS tiles.
// Operands swapped: mfma(Bt_frag, A_frag) -> lane holds 4 consecutive output
// columns (n = q*4+reg) at fixed row (m = t) -> packed 8B/16B epilogue stores.
// ---------------------------------------------------------------------------
template <int SEED_F32>
__global__ __launch_bounds__(256) void gemm3_kernel(
        const unsigned short* __restrict__ A,    // [M][K] bf16
        const unsigned short* __restrict__ Bt,   // [3D][K] bf16 (Wl^T|Wr^T|Ws^T)
        unsigned short* __restrict__ xlb,        // [M][D] bf16
        unsigned short* __restrict__ xrb,        // [M][D] bf16
        unsigned short* __restrict__ seedb,      // [M][D] bf16 (SEED_F32==0)
        float* __restrict__ seedf,               // [M][D] fp32 (SEED_F32==1)
        const float* __restrict__ b1,
        const float* __restrict__ b2,
        int M, int K, int D) {
    __shared__ __align__(16) unsigned short Asl[128 * 32];
    __shared__ __align__(16) unsigned short Bsl[128 * 32];

    int tid = threadIdx.x;
    int wave = tid >> 6, lane = tid & 63;
    int q = lane >> 4, t = lane & 15;
    int wm = (wave & 1) * 64, wn = (wave >> 1) * 64;
    int bm = blockIdx.y * 128;
    int bn_all = blockIdx.x * 128;
    int seg = bn_all / D;            // D is a multiple of 128 -> block-uniform
    int bn = bn_all - seg * D;

    // acc[jn][im]: value reg r at lane (q,t) = C[m = im*16 + t][n = jn*16 + q*4 + r]
    f32x4 acc[4][4];
#pragma unroll
    for (int i = 0; i < 4; ++i)
#pragma unroll
        for (int j = 0; j < 4; ++j) acc[i][j] = (f32x4){0.f, 0.f, 0.f, 0.f};

    for (int k0 = 0; k0 < K; k0 += 32) {
        // A tile: 128 rows x 32 k = 512 16B chunks; 256 lanes -> 2 DMA rounds
#pragma unroll
        for (int rnd = 0; rnd < 2; ++rnd) {
            int c = rnd * 256 + tid;             // per-lane chunk id
            int row = c >> 2, part = c & 3;
            int gr = bm + row; if (gr >= M) gr = M - 1;   // clamp, rows>=M unused
            gld16(A + (size_t)gr * K + k0 + part * 8,
                  Asl + (rnd * 256 + wave * 64) * 8);     // wave-uniform base
        }
        // Bt tile (3D multiple of 128 -> no guard)
#pragma unroll
        for (int rnd = 0; rnd < 2; ++rnd) {
            int c = rnd * 256 + tid;
            int row = c >> 2, part = c & 3;
            gld16(Bt + (size_t)(bn_all + row) * K + k0 + part * 8,
                  Bsl + (rnd * 256 + wave * 64) * 8);
        }
        __syncthreads();   // drains vmcnt -> DMA complete

        bf16x8 an[4], am[4];
#pragma unroll
        for (int jn = 0; jn < 4; ++jn)
            an[jn] = *(const bf16x8*)(Bsl + (wn + jn * 16 + t) * 32 + q * 8);
#pragma unroll
        for (int im = 0; im < 4; ++im)
            am[im] = *(const bf16x8*)(Asl + (wm + im * 16 + t) * 32 + q * 8);
#pragma unroll
        for (int jn = 0; jn < 4; ++jn)
#pragma unroll
            for (int im = 0; im < 4; ++im)
                acc[jn][im] = __builtin_amdgcn_mfma_f32_16x16x32_bf16(an[jn], am[im], acc[jn][im], 0, 0, 0);
        __syncthreads();   // protect LDS before next staging
    }

    // epilogue: per lane, 4 consecutive columns per (jn,im) -> packed stores
#pragma unroll
    for (int jn = 0; jn < 4; ++jn) {
        int n0 = bn + wn + jn * 16 + q * 4;
        float bx = 0.f, by = 0.f, bz = 0.f, bw = 0.f;
        if (seg == 2) {
            float4 bb1 = *(const float4*)(b1 + n0);
            float4 bb2 = *(const float4*)(b2 + n0);
            bx = bb1.x + bb2.x; by = bb1.y + bb2.y;
            bz = bb1.z + bb2.z; bw = bb1.w + bb2.w;
        }
#pragma unroll
        for (int im = 0; im < 4; ++im) {
            int m = bm + wm + im * 16 + t;
            if (m < M) {
                float v0 = acc[jn][im][0] + bx;
                float v1 = acc[jn][im][1] + by;
                float v2 = acc[jn][im][2] + bz;
                float v3 = acc[jn][im][3] + bw;
                size_t idx = (size_t)m * D + n0;
                if (seg == 2 && SEED_F32) {
                    *(float4*)(seedf + idx) = make_float4(v0, v1, v2, v3);
                } else {
                    uint2 pk;
                    pk.x = (unsigned int)f2bf(v0) | ((unsigned int)f2bf(v1) << 16);
                    pk.y = (unsigned int)f2bf(v2) | ((unsigned int)f2bf(v3) << 16);
                    unsigned short* dstp = (seg == 0) ? xlb : (seg == 1) ? xrb : seedb;
                    *(uint2*)(dstp + idx) = pk;
                }
            }
        }
    }
}

// ---------------------------------------------------------------------------
// fused per-node: edge scores + online softmax + aggregation + skip.
// One 64-lane wave per destination node, 4 edges per iteration.
// Multi-value butterfly: reduces ALL 4 edge dots in 11 shuffles (vs 24),
// one softmax rescale per 4 edges. After the keep/send tree, lane l holds
// the complete score of edge (l&3); __shfl(k,e) broadcasts each.
// ---------------------------------------------------------------------------
template <int D, int SEED_BF, int WRITE_BF, int RELU>
__global__ __launch_bounds__(256) void fused_agg_kernel(
        const unsigned short* __restrict__ xl,
        const unsigned short* __restrict__ xr,
        const float* __restrict__ att,
        const int* __restrict__ offs,
        const int* __restrict__ csr_src,
        const unsigned short* __restrict__ seedb,
        const float* __restrict__ seedf,
        float* __restrict__ outf,
        unsigned short* __restrict__ outb) {
    constexpr int VPL = D / 64;
    typedef __bf16 bvec __attribute__((ext_vector_type(VPL)));

    int wave = threadIdx.x >> 6, lane = threadIdx.x & 63;
    int n = blockIdx.x * 4 + wave;
    if (n >= N_NODES) return;
    int beg = offs[n], end = offs[n + 1];

    float xr_f[VPL], att_f[VPL];
    bvec xrv = *(const bvec*)(xr + (size_t)n * D + lane * VPL);
#pragma unroll
    for (int v = 0; v < VPL; ++v) {
        xr_f[v] = (float)xrv[v];
        att_f[v] = att[lane * VPL + v];
    }

    float acc[VPL];
#pragma unroll
    for (int v = 0; v < VPL; ++v) acc[v] = 0.f;
    float m = -INFINITY, s = 0.f;

    int b0 = lane & 1;
    int b1 = lane & 2;

    int j = beg;
    for (; j + 3 < end; j += 4) {
        int s0 = csr_src[j], s1 = csr_src[j + 1], s2 = csr_src[j + 2], s3 = csr_src[j + 3];
        bvec xv0 = *(const bvec*)(xl + (size_t)s0 * D + lane * VPL);
        bvec xv1 = *(const bvec*)(xl + (size_t)s1 * D + lane * VPL);
        bvec xv2 = *(const bvec*)(xl + (size_t)s2 * D + lane * VPL);
        bvec xv3 = *(const bvec*)(xl + (size_t)s3 * D + lane * VPL);
        float xf0[VPL], xf1[VPL], xf2[VPL], xf3[VPL];
        float p0 = 0.f, p1 = 0.f, p2 = 0.f, p3 = 0.f;
#pragma unroll
        for (int v = 0; v < VPL; ++v) {
            xf0[v] = (float)xv0[v];
            xf1[v] = (float)xv1[v];
            xf2[v] = (float)xv2[v];
            xf3[v] = (float)xv3[v];
            float t0 = xf0[v] + xr_f[v];
            float t1 = xf1[v] + xr_f[v];
            float t2 = xf2[v] + xr_f[v];
            float t3 = xf3[v] + xr_f[v];
            t0 = fmaxf(t0, 0.2f * t0);      // leaky_relu(t) == max(t, 0.2t)
            t1 = fmaxf(t1, 0.2f * t1);
            t2 = fmaxf(t2, 0.2f * t2);
            t3 = fmaxf(t3, 0.2f * t3);
            p0 += t0 * att_f[v];
            p1 += t1 * att_f[v];
            p2 += t2 * att_f[v];
            p3 += t3 * att_f[v];
        }
        // butterfly tree: stride 1 (4->2 regs), stride 2 (2->1), strides 4..32
        float k0 = b0 ? p1 : p0, sn0 = b0 ? p0 : p1;
        float k1 = b0 ? p3 : p2, sn1 = b0 ? p2 : p3;
        k0 += __shfl_xor(sn0, 1, 64);
        k1 += __shfl_xor(sn1, 1, 64);
        float k = b1 ? k1 : k0, sn = b1 ? k0 : k1;
        k += __shfl_xor(sn, 2, 64);
        k += __shfl_xor(k, 4, 64);
        k += __shfl_xor(k, 8, 64);
        k += __shfl_xor(k, 16, 64);
        k += __shfl_xor(k, 32, 64);
        // lane l now holds full score of edge (l&3); broadcast all four
        float q0 = __shfl(k, 0, 64);
        float q1 = __shfl(k, 1, 64);
        float q2 = __shfl(k, 2, 64);
        float q3 = __shfl(k, 3, 64);

        float mn = fmaxf(m, fmaxf(fmaxf(q0, q1), fmaxf(q2, q3)));
        float sc = __expf(m - mn);           // first iter: exp(-inf)=0
        float e0 = __expf(q0 - mn);
        float e1 = __expf(q1 - mn);
        float e2 = __expf(q2 - mn);
        float e3 = __expf(q3 - mn);
        s = s * sc + e0 + e1 + e2 + e3;
#pragma unroll
        for (int v = 0; v < VPL; ++v)
            acc[v] = acc[v] * sc + e0 * xf0[v] + e1 * xf1[v] + e2 * xf2[v] + e3 * xf3[v];
        m = mn;
    }
    for (; j < end; ++j) {   // tail (0-3 edges)
        int s0 = csr_src[j];
        bvec xv0 = *(const bvec*)(xl + (size_t)s0 * D + lane * VPL);
        float xf0[VPL];
        float p0 = 0.f;
#pragma unroll
        for (int v = 0; v < VPL; ++v) {
            xf0[v] = (float)xv0[v];
            float t0 = xf0[v] + xr_f[v];
            t0 = fmaxf(t0, 0.2f * t0);
            p0 += t0 * att_f[v];
        }
#pragma unroll
        for (int o = 32; o > 0; o >>= 1) p0 += __shfl_xor(p0, o, 64);
        float mn = fmaxf(m, p0);
        float sc = __expf(m - mn);
        float e0 = __expf(p0 - mn);
        s = s * sc + e0;
#pragma unroll
        for (int v = 0; v < VPL; ++v) acc[v] = acc[v] * sc + e0 * xf0[v];
        m = mn;
    }

    float sinv = 1.0f / (s + 1e-16f);
    size_t base = (size_t)n * D + lane * VPL;
    float sd[VPL];
    if (SEED_BF) {
        bvec sv = *(const bvec*)(seedb + base);
#pragma unroll
        for (int v = 0; v < VPL; ++v) sd[v] = (float)sv[v];
    } else {
#pragma unroll
        for (int v = 0; v < VPL; ++v) sd[v] = seedf[base + v];
    }
#pragma unroll
    for (int v = 0; v < VPL; ++v) {
        float val = sd[v] + acc[v] * sinv;
        if (RELU) val = fmaxf(val, 0.f);
        if (WRITE_BF) outb[base + v] = f2bf(val);
        else          outf[base + v] = val;
    }
}

// ---------------------------------------------------------------------------
// host-side layer driver
// ---------------------------------------------------------------------------
static void run_layer(const unsigned short* hbf, int K, int D,
                      const unsigned short* Wcat,
                      const float* att, const float* bc, const float* bs,
                      unsigned short* xlb, unsigned short* xrb,
                      unsigned short* seedb, float* seedf,
                      const int* offs, const int* csr_src,
                      float* outf, unsigned short* outb, int final_layer,
                      hipStream_t stream) {
    dim3 ggrid(3 * D / 128, (N_NODES + 127) / 128);
    if (final_layer)
        hipLaunchKernelGGL((gemm3_kernel<1>), ggrid, dim3(256), 0, stream, hbf, Wcat,
                           xlb, xrb, (unsigned short*)nullptr, seedf, bs, bc, N_NODES, K, D);
    else
        hipLaunchKernelGGL((gemm3_kernel<0>), ggrid, dim3(256), 0, stream, hbf, Wcat,
                           xlb, xrb, seedb, (float*)nullptr, bs, bc, N_NODES, K, D);

    dim3 agrid((N_NODES + 3) / 4);
    if (D == 512) {
        hipLaunchKernelGGL((fused_agg_kernel<512, 1, 1, 1>), agrid, dim3(256), 0, stream,
                           xlb, xrb, att, offs, csr_src, seedb, (const float*)nullptr,
                           (float*)nullptr, outb);
    } else if (D == 256) {
        hipLaunchKernelGGL((fused_agg_kernel<256, 1, 1, 1>), agrid, dim3(256), 0, stream,
                           xlb, xrb, att, offs, csr_src, seedb, (const float*)nullptr,
                           (float*)nullptr, outb);
    } else {
        hipLaunchKernelGGL((fused_agg_kernel<128, 0, 0, 0>), agrid, dim3(256), 0, stream,
                           xlb, xrb, att, offs, csr_src, (const unsigned short*)nullptr, seedf,
                           outf, (unsigned short*)nullptr);
    }
}

extern "C" void kernel_launch(void* const* d_in, const int* in_sizes, int n_in,
                              void* d_out, int out_size, void* d_ws, size_t ws_size,
                              hipStream_t stream) {
    const float* x = (const float*)d_in[0];
    const int* ei = (const int*)d_in[1];
    const int* src = ei;
    const int* dst = ei + N_EDGES;

    const float* Wl1 = (const float*)d_in[2];
    const float* Wr1 = (const float*)d_in[3];
    const float* att1 = (const float*)d_in[4];
    const float* bc1 = (const float*)d_in[5];
    const float* Ws1 = (const float*)d_in[6];
    const float* bs1 = (const float*)d_in[7];
    const float* Wl2 = (const float*)d_in[8];
    const float* Wr2 = (const float*)d_in[9];
    const float* att2 = (const float*)d_in[10];
    const float* bc2 = (const float*)d_in[11];
    const float* Ws2 = (const float*)d_in[12];
    const float* bs2 = (const float*)d_in[13];
    const float* Wl3 = (const float*)d_in[14];
    const float* Wr3 = (const float*)d_in[15];
    const float* att3 = (const float*)d_in[16];
    const float* bc3 = (const float*)d_in[17];
    const float* Ws3 = (const float*)d_in[18];
    const float* bs3 = (const float*)d_in[19];

    // workspace carve
    const size_t NF = (size_t)N_NODES * 512;
    const size_t NH = (size_t)N_NODES * 256;
    unsigned short* xlb   = (unsigned short*)d_ws;      // N x 512 bf16 (reused per layer)
    unsigned short* xrb   = xlb + NF;
    unsigned short* seedb = xrb + NF;                   // N x 512 bf16 (layers 1-2)
    unsigned short* xbf   = seedb + NF;                 // x as bf16: N x 256
    unsigned short* h1b   = xbf + NH;                   // layer1 out: N x 512
    unsigned short* h2b   = h1b + NF;                   // layer2 out: N x 256
    unsigned short* Wcat1 = h2b + NH;                   // 3 x 512 x 256
    unsigned short* Wcat2 = Wcat1 + 3 * 512 * 256;      // 3 x 256 x 512
    unsigned short* Wcat3 = Wcat2 + 3 * 256 * 512;      // 3 x 128 x 256
    int* deg     = (int*)(Wcat3 + 3 * 128 * 256);
    int* offs    = deg + N_NODES;
    int* cursor  = offs + N_NODES + 1;
    int* csr_src = cursor + N_NODES;
    size_t needed = (size_t)((char*)(csr_src + N_EDGES) - (char*)d_ws);
    if (ws_size < needed) return;

    // CSR build
    hipLaunchKernelGGL(zero_int_kernel, dim3((N_NODES + 255) / 256), dim3(256), 0, stream,
                       deg, N_NODES);
    hipLaunchKernelGGL(count_deg_kernel, dim3((N_EDGES + 255) / 256), dim3(256), 0, stream,
                       dst, deg, N_EDGES);
    hipLaunchKernelGGL(scan_kernel, dim3(1), dim3(SCAN_T), 0, stream, deg, offs, cursor, N_NODES);
    hipLaunchKernelGGL(scatter_kernel, dim3((N_EDGES + 255) / 256), dim3(256), 0, stream,
                       src, dst, cursor, csr_src, N_EDGES);

    // all weight transposes in one launch (into concatenated [Wl^T|Wr^T|Ws^T] buffers)
    {
        TransJobs jb;
        const float* Ws_[9]  = {Wl1, Wr1, Ws1, Wl2, Wr2, Ws2, Wl3, Wr3, Ws3};
        unsigned short* Wt_[9] = {Wcat1, Wcat1 + 512 * 256, Wcat1 + 2 * 512 * 256,
                                  Wcat2, Wcat2 + 256 * 512, Wcat2 + 2 * 256 * 512,
                                  Wcat3, Wcat3 + 128 * 256, Wcat3 + 2 * 128 * 256};
        int K_[9] = {256, 256, 256, 512, 512, 512, 256, 256, 256};
        int D_[9] = {512, 512, 512, 256, 256, 256, 128, 128, 128};
        int o = 0;
        for (int i = 0; i < 9; ++i) {
            jb.W[i] = Ws_[i]; jb.Wt[i] = Wt_[i]; jb.K[i] = K_[i]; jb.D[i] = D_[i];
            jb.beg[i] = o; o += K_[i] * D_[i];
        }
        jb.beg[9] = o;
        hipLaunchKernelGGL(transpose_all_kernel, dim3((o + 255) / 256), dim3(256), 0, stream, jb);
    }

    // x -> bf16
    {
        int nconv = N_NODES * 256;
        hipLaunchKernelGGL(convert_bf16_kernel, dim3((nconv / 4 + 255) / 256), dim3(256), 0, stream,
                           x, xbf, nconv);
    }

    // layer 1: 256 -> 512, relu, bf16 out
    run_layer(xbf, 256, 512, Wcat1, att1, bc1, bs1,
              xlb, xrb, seedb, (float*)nullptr, offs, csr_src,
              (float*)nullptr, h1b, 0, stream);
    // layer 2: 512 -> 256, relu, bf16 out
    run_layer(h1b, 512, 256, Wcat2, att2, bc2, bs2,
              xlb, xrb, seedb, (float*)nullptr, offs, csr_src,
              (float*)nullptr, h2b, 0, stream);
    // layer 3: 256 -> 128, no relu, fp32 out; seed directly in d_out
    run_layer(h2b, 256, 128, Wcat3, att3, bc3, bs3,
              xlb, xrb, (unsigned short*)nullptr, (float*)d_out, offs, csr_src,
              (float*)d_out, (unsigned short*)nullptr, 1, stream);
}